// Round 1
// baseline (1277.601 us; speedup 1.0000x reference)
//
#include <hip/hip_runtime.h>
#include <stdint.h>

#define NN 100000   // nodes
#define NE 400000   // edges per relation
#define NR 3        // relations
#define NF 256      // feature dim
#define NK 768      // NR*NF concatenated K
#define NG 128      // graphs

typedef __attribute__((ext_vector_type(4))) unsigned short ushortx4;
typedef __attribute__((ext_vector_type(8))) short short8;
typedef __attribute__((ext_vector_type(4))) float floatx4;

static __device__ __forceinline__ unsigned short f2bfu(float f) {
  union { float f; uint32_t u; } c; c.f = f;
  uint32_t x = c.u;
  uint32_t r = (x + 0x7fffu + ((x >> 16) & 1u)) >> 16;
  return (unsigned short)r;
}
static __device__ __forceinline__ float bfu2f(unsigned short u) {
  union { uint32_t u; float f; } c; c.u = ((uint32_t)u) << 16;
  return c.f;
}

static __device__ __forceinline__ void gload16(const void* g, void* l) {
  __builtin_amdgcn_global_load_lds(
      (const __attribute__((address_space(1))) uint32_t*)g,
      (__attribute__((address_space(3))) uint32_t*)l, 16, 0, 0);
}

// ---------------- graph preprocessing ----------------

__global__ __launch_bounds__(256) void degree_kernel(
    const int* __restrict__ src, const int* __restrict__ dst,
    int* __restrict__ deg_out, int* __restrict__ deg_in) {
  int t = blockIdx.x * 256 + threadIdx.x;
  int r = blockIdx.y;
  if (t < NE) {
    atomicAdd(&deg_out[r * NN + src[r * NE + t]], 1);
    atomicAdd(&deg_in[r * NN + dst[r * NE + t]], 1);
  }
}

__global__ __launch_bounds__(256) void gcount_kernel(
    const int* __restrict__ gid, int* __restrict__ gcount) {
  int t = blockIdx.x * 256 + threadIdx.x;
  if (t < NN) atomicAdd(&gcount[gid[t]], 1);
}

__global__ __launch_bounds__(256) void norm_kernel(
    const int* __restrict__ deg_out, const int* __restrict__ deg_in,
    float* __restrict__ n_src, float* __restrict__ n_dst) {
  int t = blockIdx.x * 256 + threadIdx.x;
  if (t < NR * NN) {
    int dof = deg_out[t], din = deg_in[t];
    n_src[t] = dof > 0 ? rsqrtf((float)dof) : 0.f;
    n_dst[t] = din > 0 ? rsqrtf((float)din) : 0.f;
  }
}

// exclusive prefix sum of deg_in -> rowptr, one block (1024 thr) per relation
__global__ __launch_bounds__(1024) void scan_kernel(
    const int* __restrict__ deg_in, int* __restrict__ rowptr) {
  int r = blockIdx.x;
  const int* deg = deg_in + r * NN;
  int* rp = rowptr + (size_t)r * (NN + 1);
  __shared__ int buf[1024];
  __shared__ int carry;
  int tid = threadIdx.x;
  if (tid == 0) carry = 0;
  __syncthreads();
  for (int base = 0; base < NN; base += 1024) {
    int i = base + tid;
    int v = (i < NN) ? deg[i] : 0;
    buf[tid] = v;
    __syncthreads();
    for (int off = 1; off < 1024; off <<= 1) {
      int t = (tid >= off) ? buf[tid - off] : 0;
      __syncthreads();
      buf[tid] += t;
      __syncthreads();
    }
    int incl = buf[tid];
    if (i < NN) rp[i] = carry + incl - v;   // exclusive
    __syncthreads();
    if (tid == 1023) carry += buf[1023];
    __syncthreads();
  }
  if (tid == 0) rp[NN] = carry;
}

__global__ __launch_bounds__(256) void scatter_kernel(
    const int* __restrict__ src, const int* __restrict__ dst,
    const int* __restrict__ rowptr, int* __restrict__ cursor,
    const float* __restrict__ n_src,
    int* __restrict__ csr_src, float* __restrict__ csr_w) {
  int t = blockIdx.x * 256 + threadIdx.x;
  int r = blockIdx.y;
  if (t < NE) {
    int s = src[r * NE + t], v = dst[r * NE + t];
    int pos = atomicAdd(&cursor[r * NN + v], 1);
    int idx = r * NE + rowptr[(size_t)r * (NN + 1) + v] + pos;
    csr_src[idx] = s;
    csr_w[idx] = n_src[r * NN + s];
  }
}

// ---------------- weight / feature prep ----------------

// wt[layer][n][r*256+k] = W[layer][r][k][n]  (bf16, B^T layout for GEMM)
__global__ __launch_bounds__(256) void prep_w_kernel(
    const float* __restrict__ W1, const float* __restrict__ W2,
    unsigned short* __restrict__ wt1, unsigned short* __restrict__ wt2) {
  int t = blockIdx.x * 256 + threadIdx.x;   // 2*3*256*256
  int lay = t / (NR * NF * NF);
  int rem = t % (NR * NF * NF);
  int r = rem / (NF * NF);
  int k = (rem / NF) % NF;
  int n = rem % NF;
  const float* W = lay ? W2 : W1;
  unsigned short* wt = lay ? wt2 : wt1;
  wt[(size_t)n * NK + r * NF + k] = f2bfu(W[((size_t)r * NF + k) * NF + n]);
}

__global__ __launch_bounds__(256) void prep_bias_kernel(
    const float* __restrict__ b1, const float* __restrict__ b2,
    float* __restrict__ bs1, float* __restrict__ bs2) {
  int t = blockIdx.x * 256 + threadIdx.x;   // 512
  if (t < 2 * NF) {
    int lay = t / NF, n = t % NF;
    const float* b = lay ? b2 : b1;
    float* bs = lay ? bs2 : bs1;
    bs[n] = b[n] + b[NF + n] + b[2 * NF + n];
  }
}

__global__ __launch_bounds__(256) void cast_kernel(
    const float* __restrict__ in, unsigned short* __restrict__ out, int n4) {
  int t = blockIdx.x * 256 + threadIdx.x;
  if (t < n4) {
    floatx4 v = *(const floatx4*)&in[(size_t)t * 4];
    ushortx4 o;
    o.x = f2bfu(v.x); o.y = f2bfu(v.y); o.z = f2bfu(v.z); o.w = f2bfu(v.w);
    *(ushortx4*)&out[(size_t)t * 4] = o;
  }
}

// ---------------- SpMM: one wave per (node, relation), pull via CSR ----------------

__global__ __launch_bounds__(256) void spmm_kernel(
    const unsigned short* __restrict__ x,   // [NN][256] bf16
    const int* __restrict__ rowptr, const int* __restrict__ csr_src,
    const float* __restrict__ csr_w, const float* __restrict__ n_dst,
    unsigned short* __restrict__ agg) {     // [NN][768] bf16
  int wid = threadIdx.x >> 6, l = threadIdx.x & 63;
  int r = blockIdx.y;
  int v = blockIdx.x * 4 + wid;
  if (v >= NN) return;
  int e0 = rowptr[(size_t)r * (NN + 1) + v];
  int e1 = rowptr[(size_t)r * (NN + 1) + v + 1];
  const int* cs = csr_src + (size_t)r * NE;
  const float* cw = csr_w + (size_t)r * NE;
  float a0 = 0.f, a1 = 0.f, a2 = 0.f, a3 = 0.f;
  for (int e = e0; e < e1; ++e) {
    int s = cs[e];
    float w = cw[e];
    ushortx4 xv = *(const ushortx4*)&x[(size_t)s * NF + l * 4];
    a0 += w * bfu2f(xv.x);
    a1 += w * bfu2f(xv.y);
    a2 += w * bfu2f(xv.z);
    a3 += w * bfu2f(xv.w);
  }
  float nd = n_dst[r * NN + v];
  ushortx4 o;
  o.x = f2bfu(a0 * nd); o.y = f2bfu(a1 * nd);
  o.z = f2bfu(a2 * nd); o.w = f2bfu(a3 * nd);
  *(ushortx4*)&agg[(size_t)v * NK + r * NF + l * 4] = o;
}

// ---------------- GEMM: [M,768] @ [768,256] bf16 MFMA (m97 128x128 structure) ----------------

__global__ __launch_bounds__(256) void gemm_kernel(
    const unsigned short* __restrict__ A,    // [M][768] bf16
    const unsigned short* __restrict__ Bt,   // [256][768] bf16 (B^T)
    const float* __restrict__ bias,          // [256]
    unsigned short* __restrict__ C,          // [M][256] bf16
    int M, int relu) {
  __shared__ unsigned short ldsA[128 * 32];
  __shared__ unsigned short ldsB[128 * 32];
  const int tid = threadIdx.x;
  const int l = tid & 63, wid = tid >> 6;
  const int wr = wid >> 1, wc = wid & 1;
  const int row0 = blockIdx.x * 128, col0 = blockIdx.y * 128;

  floatx4 acc[4][4];
#pragma unroll
  for (int i = 0; i < 4; ++i)
#pragma unroll
    for (int j = 0; j < 4; ++j)
#pragma unroll
      for (int q = 0; q < 4; ++q) acc[i][j][q] = 0.f;

  const int srow = l >> 2;          // staging: row within 16-row chunk
  const int skc = (l & 3) * 8;      // staging: k offset (8 bf16 = 16B)
  const int fr = l & 15, fk = (l >> 4) * 8;

  for (int kt = 0; kt < NK / 32; ++kt) {
    const int k0 = kt * 32;
#pragma unroll
    for (int it = 0; it < 2; ++it) {
      int ci = it * 4 + wid;                     // chunk 0..7 (16 rows each)
      int arow = row0 + ci * 16 + srow;
      if (arow >= M) arow = M - 1;               // clamp, masked at store
      gload16(A + (size_t)arow * NK + k0 + skc, &ldsA[ci * 512 + l * 8]);
      int brow = col0 + ci * 16 + srow;          // N=256 exact
      gload16(Bt + (size_t)brow * NK + k0 + skc, &ldsB[ci * 512 + l * 8]);
    }
    asm volatile("s_waitcnt vmcnt(0)" ::: "memory");
    __syncthreads();

    short8 af[4], bf[4];
#pragma unroll
    for (int m = 0; m < 4; ++m)
      af[m] = *(const short8*)&ldsA[(wr * 64 + m * 16 + fr) * 32 + fk];
#pragma unroll
    for (int n = 0; n < 4; ++n)
      bf[n] = *(const short8*)&ldsB[(wc * 64 + n * 16 + fr) * 32 + fk];
#pragma unroll
    for (int m = 0; m < 4; ++m)
#pragma unroll
      for (int n = 0; n < 4; ++n)
        acc[m][n] = __builtin_amdgcn_mfma_f32_16x16x32_bf16(af[m], bf[n], acc[m][n], 0, 0, 0);
    __syncthreads();
  }

  const int fq = l >> 4;
#pragma unroll
  for (int m = 0; m < 4; ++m) {
#pragma unroll
    for (int n = 0; n < 4; ++n) {
      int col = col0 + wc * 64 + n * 16 + fr;
      float bv = bias[col];
#pragma unroll
      for (int q = 0; q < 4; ++q) {
        int row = row0 + wr * 64 + m * 16 + fq * 4 + q;
        if (row < M) {
          float vv = acc[m][n][q] + bv;
          if (relu) vv = fmaxf(vv, 0.f);
          C[(size_t)row * NF + col] = f2bfu(vv);
        }
      }
    }
  }
}

// ---------------- pooling ----------------

__global__ __launch_bounds__(256) void pool_kernel(
    const unsigned short* __restrict__ h2, const int* __restrict__ gid,
    float* __restrict__ poolsum) {
  int c = threadIdx.x;                 // column 0..255
  int v0 = blockIdx.x * 256;
  int vend = min(v0 + 256, NN);
  float acc = 0.f;
  int curg = -1;
  for (int v = v0; v < vend; ++v) {
    int g = gid[v];                    // sorted -> few runs per chunk
    if (g != curg) {
      if (curg >= 0) atomicAdd(&poolsum[curg * NF + c], acc);
      curg = g; acc = 0.f;
    }
    acc += bfu2f(h2[(size_t)v * NF + c]);
  }
  if (curg >= 0) atomicAdd(&poolsum[curg * NF + c], acc);
}

__global__ __launch_bounds__(256) void final_kernel(
    const float* __restrict__ poolsum, const int* __restrict__ gcount,
    float* __restrict__ out) {
  int g = blockIdx.x, c = threadIdx.x;
  out[g * NF + c] = poolsum[g * NF + c] / fmaxf((float)gcount[g], 1.f);
}

// ---------------- launch ----------------

extern "C" void kernel_launch(void* const* d_in, const int* in_sizes, int n_in,
                              void* d_out, int out_size, void* d_ws, size_t ws_size,
                              hipStream_t stream) {
  const float* feat = (const float*)d_in[0];
  const int* src = (const int*)d_in[1];
  const int* dst = (const int*)d_in[2];
  const int* gid = (const int*)d_in[3];
  const float* W1 = (const float*)d_in[4];
  const float* b1 = (const float*)d_in[5];
  const float* W2 = (const float*)d_in[6];
  const float* b2 = (const float*)d_in[7];
  float* out = (float*)d_out;

  char* ws = (char*)d_ws;
  size_t off = 0;
  auto alloc = [&](size_t bytes) -> void* {
    void* p = ws + off;
    off = (off + bytes + 255) & ~(size_t)255;
    return p;
  };

  // zero-initialized block (single memset)
  int* deg_out = (int*)alloc((size_t)NR * NN * 4);
  int* deg_in  = (int*)alloc((size_t)NR * NN * 4);
  int* cursor  = (int*)alloc((size_t)NR * NN * 4);
  int* gcount  = (int*)alloc((size_t)NG * 4);
  float* poolsum = (float*)alloc((size_t)NG * NF * 4);
  size_t zero_bytes = off;

  float* n_src = (float*)alloc((size_t)NR * NN * 4);
  float* n_dst = (float*)alloc((size_t)NR * NN * 4);
  int* rowptr  = (int*)alloc((size_t)NR * (NN + 1) * 4);
  int* csr_src = (int*)alloc((size_t)NR * NE * 4);
  float* csr_w = (float*)alloc((size_t)NR * NE * 4);
  unsigned short* wt1 = (unsigned short*)alloc((size_t)NF * NK * 2);
  unsigned short* wt2 = (unsigned short*)alloc((size_t)NF * NK * 2);
  float* bs1 = (float*)alloc(NF * 4);
  float* bs2 = (float*)alloc(NF * 4);
  unsigned short* featbf = (unsigned short*)alloc((size_t)NN * NF * 2);
  unsigned short* h1 = (unsigned short*)alloc((size_t)NN * NF * 2);
  unsigned short* h2 = (unsigned short*)alloc((size_t)NN * NF * 2);
  unsigned short* agg = (unsigned short*)alloc((size_t)NN * NK * 2);
  (void)ws_size; (void)in_sizes; (void)n_in; (void)out_size;

  hipMemsetAsync(d_ws, 0, zero_bytes, stream);

  dim3 eg((NE + 255) / 256, NR);
  degree_kernel<<<eg, 256, 0, stream>>>(src, dst, deg_out, deg_in);
  gcount_kernel<<<(NN + 255) / 256, 256, 0, stream>>>(gid, gcount);
  norm_kernel<<<(NR * NN + 255) / 256, 256, 0, stream>>>(deg_out, deg_in, n_src, n_dst);
  scan_kernel<<<NR, 1024, 0, stream>>>(deg_in, rowptr);
  scatter_kernel<<<eg, 256, 0, stream>>>(src, dst, rowptr, cursor, n_src, csr_src, csr_w);

  prep_w_kernel<<<(2 * NR * NF * NF) / 256, 256, 0, stream>>>(W1, W2, wt1, wt2);
  prep_bias_kernel<<<2, 256, 0, stream>>>(b1, b2, bs1, bs2);
  cast_kernel<<<(NN * NF / 4 + 255) / 256, 256, 0, stream>>>(feat, featbf, NN * NF / 4);

  dim3 sg((NN + 3) / 4, NR);
  // layer 1
  spmm_kernel<<<sg, 256, 0, stream>>>(featbf, rowptr, csr_src, csr_w, n_dst, agg);
  gemm_kernel<<<dim3((NN + 127) / 128, 2), 256, 0, stream>>>(agg, wt1, bs1, h1, NN, 1);
  // layer 2
  spmm_kernel<<<sg, 256, 0, stream>>>(h1, rowptr, csr_src, csr_w, n_dst, agg);
  gemm_kernel<<<dim3((NN + 127) / 128, 2), 256, 0, stream>>>(agg, wt2, bs2, h2, NN, 0);
  // pooling
  pool_kernel<<<(NN + 255) / 256, 256, 0, stream>>>(h2, gid, poolsum);
  final_kernel<<<NG, 256, 0, stream>>>(poolsum, gcount, out);
}

// Round 2
// 1000.806 us; speedup vs baseline: 1.2766x; 1.2766x over previous
//
#include <hip/hip_runtime.h>
#include <stdint.h>

#define NN 100000   // nodes
#define NE 400000   // edges per relation
#define NR 3        // relations
#define NF 256      // feature dim
#define NK 768      // NR*NF concatenated K
#define NG 128      // graphs

typedef __attribute__((ext_vector_type(4))) unsigned short ushortx4;
typedef __attribute__((ext_vector_type(8))) short short8;
typedef __attribute__((ext_vector_type(4))) float floatx4;

static __device__ __forceinline__ unsigned short f2bfu(float f) {
  union { float f; uint32_t u; } c; c.f = f;
  uint32_t x = c.u;
  uint32_t r = (x + 0x7fffu + ((x >> 16) & 1u)) >> 16;
  return (unsigned short)r;
}
static __device__ __forceinline__ float bfu2f(unsigned short u) {
  union { uint32_t u; float f; } c; c.u = ((uint32_t)u) << 16;
  return c.f;
}

static __device__ __forceinline__ void gload16(const void* g, void* l) {
  __builtin_amdgcn_global_load_lds(
      (const __attribute__((address_space(1))) uint32_t*)g,
      (__attribute__((address_space(3))) uint32_t*)l, 16, 0, 0);
}

// ---------------- graph preprocessing ----------------

__global__ __launch_bounds__(256) void degree_kernel(
    const int* __restrict__ src, const int* __restrict__ dst,
    int* __restrict__ deg_out, int* __restrict__ deg_in) {
  int t = blockIdx.x * 256 + threadIdx.x;
  int r = blockIdx.y;
  if (t < NE) {
    atomicAdd(&deg_out[r * NN + src[r * NE + t]], 1);
    atomicAdd(&deg_in[r * NN + dst[r * NE + t]], 1);
  }
}

// gid is sorted: count[g] = lb(g+1) - lb(g) via binary search. No atomics.
__global__ __launch_bounds__(128) void gcount_kernel(
    const int* __restrict__ gid, int* __restrict__ gcount) {
  int g = threadIdx.x;  // 0..127
  int lo = 0, hi = NN;
  while (lo < hi) { int mid = (lo + hi) >> 1; if (gid[mid] < g) lo = mid + 1; else hi = mid; }
  int a = lo;
  lo = 0; hi = NN;
  while (lo < hi) { int mid = (lo + hi) >> 1; if (gid[mid] < g + 1) lo = mid + 1; else hi = mid; }
  gcount[g] = lo - a;
}

__global__ __launch_bounds__(256) void norm_kernel(
    const int* __restrict__ deg_out, const int* __restrict__ deg_in,
    float* __restrict__ n_src, float* __restrict__ n_dst) {
  int t = blockIdx.x * 256 + threadIdx.x;
  if (t < NR * NN) {
    int dof = deg_out[t], din = deg_in[t];
    n_src[t] = dof > 0 ? rsqrtf((float)dof) : 0.f;
    n_dst[t] = din > 0 ? rsqrtf((float)din) : 0.f;
  }
}

// exclusive prefix sum of deg_in -> rowptr, one block (1024 thr) per relation
__global__ __launch_bounds__(1024) void scan_kernel(
    const int* __restrict__ deg_in, int* __restrict__ rowptr) {
  int r = blockIdx.x;
  const int* deg = deg_in + r * NN;
  int* rp = rowptr + (size_t)r * (NN + 1);
  __shared__ int buf[1024];
  __shared__ int carry;
  int tid = threadIdx.x;
  if (tid == 0) carry = 0;
  __syncthreads();
  for (int base = 0; base < NN; base += 1024) {
    int i = base + tid;
    int v = (i < NN) ? deg[i] : 0;
    buf[tid] = v;
    __syncthreads();
    for (int off = 1; off < 1024; off <<= 1) {
      int t = (tid >= off) ? buf[tid - off] : 0;
      __syncthreads();
      buf[tid] += t;
      __syncthreads();
    }
    int incl = buf[tid];
    if (i < NN) rp[i] = carry + incl - v;   // exclusive
    __syncthreads();
    if (tid == 1023) carry += buf[1023];
    __syncthreads();
  }
  if (tid == 0) rp[NN] = carry;
}

__global__ __launch_bounds__(256) void scatter_kernel(
    const int* __restrict__ src, const int* __restrict__ dst,
    const int* __restrict__ rowptr, int* __restrict__ cursor,
    const float* __restrict__ n_src,
    int* __restrict__ csr_src, float* __restrict__ csr_w) {
  int t = blockIdx.x * 256 + threadIdx.x;
  int r = blockIdx.y;
  if (t < NE) {
    int s = src[r * NE + t], v = dst[r * NE + t];
    int pos = atomicAdd(&cursor[r * NN + v], 1);
    int idx = r * NE + rowptr[(size_t)r * (NN + 1) + v] + pos;
    csr_src[idx] = s;
    csr_w[idx] = n_src[r * NN + s];
  }
}

// ---------------- weight / feature prep ----------------

// wt[layer][n][r*256+k] = W[layer][r][k][n]  (bf16, B^T layout for GEMM)
__global__ __launch_bounds__(256) void prep_w_kernel(
    const float* __restrict__ W1, const float* __restrict__ W2,
    unsigned short* __restrict__ wt1, unsigned short* __restrict__ wt2) {
  int t = blockIdx.x * 256 + threadIdx.x;   // 2*3*256*256
  int lay = t / (NR * NF * NF);
  int rem = t % (NR * NF * NF);
  int r = rem / (NF * NF);
  int k = (rem / NF) % NF;
  int n = rem % NF;
  const float* W = lay ? W2 : W1;
  unsigned short* wt = lay ? wt2 : wt1;
  wt[(size_t)n * NK + r * NF + k] = f2bfu(W[((size_t)r * NF + k) * NF + n]);
}

__global__ __launch_bounds__(256) void prep_bias_kernel(
    const float* __restrict__ b1, const float* __restrict__ b2,
    float* __restrict__ bs1, float* __restrict__ bs2) {
  int t = blockIdx.x * 256 + threadIdx.x;   // 512
  if (t < 2 * NF) {
    int lay = t / NF, n = t % NF;
    const float* b = lay ? b2 : b1;
    float* bs = lay ? bs2 : bs1;
    bs[n] = b[n] + b[NF + n] + b[2 * NF + n];
  }
}

__global__ __launch_bounds__(256) void cast_kernel(
    const float* __restrict__ in, unsigned short* __restrict__ out, int n4) {
  int t = blockIdx.x * 256 + threadIdx.x;
  if (t < n4) {
    floatx4 v = *(const floatx4*)&in[(size_t)t * 4];
    ushortx4 o;
    o.x = f2bfu(v.x); o.y = f2bfu(v.y); o.z = f2bfu(v.z); o.w = f2bfu(v.w);
    *(ushortx4*)&out[(size_t)t * 4] = o;
  }
}

// ---------------- SpMM: one wave per (node, relation), pull via CSR ----------------

__global__ __launch_bounds__(256) void spmm_kernel(
    const unsigned short* __restrict__ x,   // [NN][256] bf16
    const int* __restrict__ rowptr, const int* __restrict__ csr_src,
    const float* __restrict__ csr_w, const float* __restrict__ n_dst,
    unsigned short* __restrict__ agg) {     // [NN][768] bf16
  int wid = threadIdx.x >> 6, l = threadIdx.x & 63;
  int r = blockIdx.y;
  int v = blockIdx.x * 4 + wid;
  if (v >= NN) return;
  int e0 = rowptr[(size_t)r * (NN + 1) + v];
  int e1 = rowptr[(size_t)r * (NN + 1) + v + 1];
  const int* cs = csr_src + (size_t)r * NE;
  const float* cw = csr_w + (size_t)r * NE;
  float a0 = 0.f, a1 = 0.f, a2 = 0.f, a3 = 0.f;
  for (int e = e0; e < e1; ++e) {
    int s = cs[e];
    float w = cw[e];
    ushortx4 xv = *(const ushortx4*)&x[(size_t)s * NF + l * 4];
    a0 += w * bfu2f(xv.x);
    a1 += w * bfu2f(xv.y);
    a2 += w * bfu2f(xv.z);
    a3 += w * bfu2f(xv.w);
  }
  float nd = n_dst[r * NN + v];
  ushortx4 o;
  o.x = f2bfu(a0 * nd); o.y = f2bfu(a1 * nd);
  o.z = f2bfu(a2 * nd); o.w = f2bfu(a3 * nd);
  *(ushortx4*)&agg[(size_t)v * NK + r * NF + l * 4] = o;
}

// ---------------- GEMM: [M,768] @ [768,256] bf16 MFMA (m97 128x128 structure) ----------------

__global__ __launch_bounds__(256) void gemm_kernel(
    const unsigned short* __restrict__ A,    // [M][768] bf16
    const unsigned short* __restrict__ Bt,   // [256][768] bf16 (B^T)
    const float* __restrict__ bias,          // [256]
    unsigned short* __restrict__ C,          // [M][256] bf16
    int M, int relu) {
  __shared__ unsigned short ldsA[128 * 32];
  __shared__ unsigned short ldsB[128 * 32];
  const int tid = threadIdx.x;
  const int l = tid & 63, wid = tid >> 6;
  const int wr = wid >> 1, wc = wid & 1;
  const int row0 = blockIdx.x * 128, col0 = blockIdx.y * 128;

  floatx4 acc[4][4];
#pragma unroll
  for (int i = 0; i < 4; ++i)
#pragma unroll
    for (int j = 0; j < 4; ++j)
#pragma unroll
      for (int q = 0; q < 4; ++q) acc[i][j][q] = 0.f;

  const int srow = l >> 2;          // staging: row within 16-row chunk
  const int skc = (l & 3) * 8;      // staging: k offset (8 bf16 = 16B)
  const int fr = l & 15, fk = (l >> 4) * 8;

  for (int kt = 0; kt < NK / 32; ++kt) {
    const int k0 = kt * 32;
#pragma unroll
    for (int it = 0; it < 2; ++it) {
      int ci = it * 4 + wid;                     // chunk 0..7 (16 rows each)
      int arow = row0 + ci * 16 + srow;
      if (arow >= M) arow = M - 1;               // clamp, masked at store
      gload16(A + (size_t)arow * NK + k0 + skc, &ldsA[ci * 512 + l * 8]);
      int brow = col0 + ci * 16 + srow;          // N=256 exact
      gload16(Bt + (size_t)brow * NK + k0 + skc, &ldsB[ci * 512 + l * 8]);
    }
    asm volatile("s_waitcnt vmcnt(0)" ::: "memory");
    __syncthreads();

    short8 af[4], bf[4];
#pragma unroll
    for (int m = 0; m < 4; ++m)
      af[m] = *(const short8*)&ldsA[(wr * 64 + m * 16 + fr) * 32 + fk];
#pragma unroll
    for (int n = 0; n < 4; ++n)
      bf[n] = *(const short8*)&ldsB[(wc * 64 + n * 16 + fr) * 32 + fk];
#pragma unroll
    for (int m = 0; m < 4; ++m)
#pragma unroll
      for (int n = 0; n < 4; ++n)
        acc[m][n] = __builtin_amdgcn_mfma_f32_16x16x32_bf16(af[m], bf[n], acc[m][n], 0, 0, 0);
    __syncthreads();
  }

  const int fq = l >> 4;
#pragma unroll
  for (int m = 0; m < 4; ++m) {
#pragma unroll
    for (int n = 0; n < 4; ++n) {
      int col = col0 + wc * 64 + n * 16 + fr;
      float bv = bias[col];
#pragma unroll
      for (int q = 0; q < 4; ++q) {
        int row = row0 + wr * 64 + m * 16 + fq * 4 + q;
        if (row < M) {
          float vv = acc[m][n][q] + bv;
          if (relu) vv = fmaxf(vv, 0.f);
          C[(size_t)row * NF + col] = f2bfu(vv);
        }
      }
    }
  }
}

// ---------------- pooling ----------------

__global__ __launch_bounds__(256) void pool_kernel(
    const unsigned short* __restrict__ h2, const int* __restrict__ gid,
    float* __restrict__ poolsum) {
  int c = threadIdx.x;                 // column 0..255
  int v0 = blockIdx.x * 256;
  int vend = min(v0 + 256, NN);
  float acc = 0.f;
  int curg = -1;
  for (int v = v0; v < vend; ++v) {
    int g = gid[v];                    // sorted -> few runs per chunk
    if (g != curg) {
      if (curg >= 0) atomicAdd(&poolsum[curg * NF + c], acc);
      curg = g; acc = 0.f;
    }
    acc += bfu2f(h2[(size_t)v * NF + c]);
  }
  if (curg >= 0) atomicAdd(&poolsum[curg * NF + c], acc);
}

__global__ __launch_bounds__(256) void final_kernel(
    const float* __restrict__ poolsum, const int* __restrict__ gcount,
    float* __restrict__ out) {
  int g = blockIdx.x, c = threadIdx.x;
  out[g * NF + c] = poolsum[g * NF + c] / fmaxf((float)gcount[g], 1.f);
}

// ---------------- launch ----------------

extern "C" void kernel_launch(void* const* d_in, const int* in_sizes, int n_in,
                              void* d_out, int out_size, void* d_ws, size_t ws_size,
                              hipStream_t stream) {
  const float* feat = (const float*)d_in[0];
  const int* src = (const int*)d_in[1];
  const int* dst = (const int*)d_in[2];
  const int* gid = (const int*)d_in[3];
  const float* W1 = (const float*)d_in[4];
  const float* b1 = (const float*)d_in[5];
  const float* W2 = (const float*)d_in[6];
  const float* b2 = (const float*)d_in[7];
  float* out = (float*)d_out;

  char* ws = (char*)d_ws;
  size_t off = 0;
  auto alloc = [&](size_t bytes) -> void* {
    void* p = ws + off;
    off = (off + bytes + 255) & ~(size_t)255;
    return p;
  };

  // zero-initialized block (single memset)
  int* deg_out = (int*)alloc((size_t)NR * NN * 4);
  int* deg_in  = (int*)alloc((size_t)NR * NN * 4);
  int* cursor  = (int*)alloc((size_t)NR * NN * 4);
  int* gcount  = (int*)alloc((size_t)NG * 4);
  float* poolsum = (float*)alloc((size_t)NG * NF * 4);
  size_t zero_bytes = off;

  float* n_src = (float*)alloc((size_t)NR * NN * 4);
  float* n_dst = (float*)alloc((size_t)NR * NN * 4);
  int* rowptr  = (int*)alloc((size_t)NR * (NN + 1) * 4);
  int* csr_src = (int*)alloc((size_t)NR * NE * 4);
  float* csr_w = (float*)alloc((size_t)NR * NE * 4);
  unsigned short* wt1 = (unsigned short*)alloc((size_t)NF * NK * 2);
  unsigned short* wt2 = (unsigned short*)alloc((size_t)NF * NK * 2);
  float* bs1 = (float*)alloc(NF * 4);
  float* bs2 = (float*)alloc(NF * 4);
  unsigned short* featbf = (unsigned short*)alloc((size_t)NN * NF * 2);
  unsigned short* h1 = (unsigned short*)alloc((size_t)NN * NF * 2);
  unsigned short* h2 = (unsigned short*)alloc((size_t)NN * NF * 2);
  unsigned short* agg = (unsigned short*)alloc((size_t)NN * NK * 2);
  (void)ws_size; (void)in_sizes; (void)n_in; (void)out_size;

  hipMemsetAsync(d_ws, 0, zero_bytes, stream);

  dim3 eg((NE + 255) / 256, NR);
  degree_kernel<<<eg, 256, 0, stream>>>(src, dst, deg_out, deg_in);
  gcount_kernel<<<1, 128, 0, stream>>>(gid, gcount);
  norm_kernel<<<(NR * NN + 255) / 256, 256, 0, stream>>>(deg_out, deg_in, n_src, n_dst);
  scan_kernel<<<NR, 1024, 0, stream>>>(deg_in, rowptr);
  scatter_kernel<<<eg, 256, 0, stream>>>(src, dst, rowptr, cursor, n_src, csr_src, csr_w);

  prep_w_kernel<<<(2 * NR * NF * NF) / 256, 256, 0, stream>>>(W1, W2, wt1, wt2);
  prep_bias_kernel<<<2, 256, 0, stream>>>(b1, b2, bs1, bs2);
  cast_kernel<<<(NN * NF / 4 + 255) / 256, 256, 0, stream>>>(feat, featbf, NN * NF / 4);

  dim3 sg((NN + 3) / 4, NR);
  // layer 1
  spmm_kernel<<<sg, 256, 0, stream>>>(featbf, rowptr, csr_src, csr_w, n_dst, agg);
  gemm_kernel<<<dim3((NN + 127) / 128, 2), 256, 0, stream>>>(agg, wt1, bs1, h1, NN, 1);
  // layer 2
  spmm_kernel<<<sg, 256, 0, stream>>>(h1, rowptr, csr_src, csr_w, n_dst, agg);
  gemm_kernel<<<dim3((NN + 127) / 128, 2), 256, 0, stream>>>(agg, wt2, bs2, h2, NN, 0);
  // pooling
  pool_kernel<<<(NN + 255) / 256, 256, 0, stream>>>(h2, gid, poolsum);
  final_kernel<<<NG, 256, 0, stream>>>(poolsum, gcount, out);
}

// Round 3
// 841.529 us; speedup vs baseline: 1.5182x; 1.1893x over previous
//
#include <hip/hip_runtime.h>
#include <stdint.h>

#define NN 100000   // nodes
#define NE 400000   // edges per relation
#define NR 3        // relations
#define NF 256      // feature dim
#define NK 768      // NR*NF concatenated K
#define NG 128      // graphs
#define SCAN_NB ((NN + 1023) / 1024)   // 98 chunks of 1024

typedef __attribute__((ext_vector_type(4))) unsigned short ushortx4;
typedef __attribute__((ext_vector_type(8))) short short8;
typedef __attribute__((ext_vector_type(4))) float floatx4;

static __device__ __forceinline__ unsigned short f2bfu(float f) {
  union { float f; uint32_t u; } c; c.f = f;
  uint32_t x = c.u;
  uint32_t r = (x + 0x7fffu + ((x >> 16) & 1u)) >> 16;
  return (unsigned short)r;
}
static __device__ __forceinline__ float bfu2f(unsigned short u) {
  union { uint32_t u; float f; } c; c.u = ((uint32_t)u) << 16;
  return c.f;
}

static __device__ __forceinline__ void gload16(const void* g, void* l) {
  __builtin_amdgcn_global_load_lds(
      (const __attribute__((address_space(1))) uint32_t*)g,
      (__attribute__((address_space(3))) uint32_t*)l, 16, 0, 0);
}

// ---------------- graph preprocessing ----------------

__global__ __launch_bounds__(256) void degree_kernel(
    const int* __restrict__ src, const int* __restrict__ dst,
    int* __restrict__ deg_out, int* __restrict__ deg_in) {
  int t = blockIdx.x * 256 + threadIdx.x;
  int r = blockIdx.y;
  if (t < NE) {
    atomicAdd(&deg_out[r * NN + src[r * NE + t]], 1);
    atomicAdd(&deg_in[r * NN + dst[r * NE + t]], 1);
  }
}

// gid is sorted: count[g] = lb(g+1) - lb(g) via binary search. No atomics.
__global__ __launch_bounds__(128) void gcount_kernel(
    const int* __restrict__ gid, int* __restrict__ gcount) {
  int g = threadIdx.x;  // 0..127
  int lo = 0, hi = NN;
  while (lo < hi) { int mid = (lo + hi) >> 1; if (gid[mid] < g) lo = mid + 1; else hi = mid; }
  int a = lo;
  lo = 0; hi = NN;
  while (lo < hi) { int mid = (lo + hi) >> 1; if (gid[mid] < g + 1) lo = mid + 1; else hi = mid; }
  gcount[g] = lo - a;
}

__global__ __launch_bounds__(256) void norm_kernel(
    const int* __restrict__ deg_out, const int* __restrict__ deg_in,
    float* __restrict__ n_src, float* __restrict__ n_dst) {
  int t = blockIdx.x * 256 + threadIdx.x;
  if (t < NR * NN) {
    int dof = deg_out[t], din = deg_in[t];
    n_src[t] = dof > 0 ? rsqrtf((float)dof) : 0.f;
    n_dst[t] = din > 0 ? rsqrtf((float)din) : 0.f;
  }
}

// ---- multi-block exclusive scan of deg_in -> rowptr (3 phases) ----

// Phase A: per-1024-chunk sums
__global__ __launch_bounds__(256) void scan_phaseA(
    const int* __restrict__ deg_in, int* __restrict__ blocksum) {
  int r = blockIdx.y, b = blockIdx.x, tid = threadIdx.x;
  const int* deg = deg_in + (size_t)r * NN;
  int base = b * 1024 + tid * 4;
  int s = 0;
#pragma unroll
  for (int i = 0; i < 4; ++i) { int idx = base + i; if (idx < NN) s += deg[idx]; }
  __shared__ int red[256];
  red[tid] = s; __syncthreads();
  for (int off = 128; off > 0; off >>= 1) {
    if (tid < off) red[tid] += red[tid + off];
    __syncthreads();
  }
  if (tid == 0) blocksum[r * SCAN_NB + b] = red[0];
}

// Phase B: exclusive scan of the 98 chunk sums per relation; writes rowptr[NN]
__global__ __launch_bounds__(128) void scan_phaseB(
    int* __restrict__ blocksum, int* __restrict__ rowptr) {
  int r = blockIdx.x, tid = threadIdx.x;
  int* bs = blocksum + r * SCAN_NB;
  __shared__ int buf[128];
  int v = (tid < SCAN_NB) ? bs[tid] : 0;
  buf[tid] = v; __syncthreads();
  for (int off = 1; off < 128; off <<= 1) {
    int t = (tid >= off) ? buf[tid - off] : 0;
    __syncthreads();
    buf[tid] += t;
    __syncthreads();
  }
  if (tid < SCAN_NB) bs[tid] = buf[tid] - v;   // exclusive chunk offset
  if (tid == 127) rowptr[(size_t)r * (NN + 1) + NN] = buf[127];
}

// Phase C: local exclusive scan within chunk + chunk offset
__global__ __launch_bounds__(256) void scan_phaseC(
    const int* __restrict__ deg_in, const int* __restrict__ blocksum,
    int* __restrict__ rowptr) {
  int r = blockIdx.y, b = blockIdx.x, tid = threadIdx.x;
  const int* deg = deg_in + (size_t)r * NN;
  int* rp = rowptr + (size_t)r * (NN + 1);
  int base = b * 1024 + tid * 4;
  int v[4]; int s = 0;
#pragma unroll
  for (int i = 0; i < 4; ++i) { int idx = base + i; v[i] = (idx < NN) ? deg[idx] : 0; s += v[i]; }
  __shared__ int buf[256];
  buf[tid] = s; __syncthreads();
  for (int off = 1; off < 256; off <<= 1) {
    int t = (tid >= off) ? buf[tid - off] : 0;
    __syncthreads();
    buf[tid] += t;
    __syncthreads();
  }
  int excl = buf[tid] - s + blocksum[r * SCAN_NB + b];
#pragma unroll
  for (int i = 0; i < 4; ++i) {
    int idx = base + i;
    if (idx < NN) rp[idx] = excl;
    excl += v[i];
  }
}

__global__ __launch_bounds__(256) void scatter_kernel(
    const int* __restrict__ src, const int* __restrict__ dst,
    const int* __restrict__ rowptr, int* __restrict__ cursor,
    const float* __restrict__ n_src,
    int* __restrict__ csr_src, float* __restrict__ csr_w) {
  int t = blockIdx.x * 256 + threadIdx.x;
  int r = blockIdx.y;
  if (t < NE) {
    int s = src[r * NE + t], v = dst[r * NE + t];
    int pos = atomicAdd(&cursor[r * NN + v], 1);
    int idx = r * NE + rowptr[(size_t)r * (NN + 1) + v] + pos;
    csr_src[idx] = s;
    csr_w[idx] = n_src[r * NN + s];
  }
}

// ---------------- weight / feature prep ----------------

// wt[layer][n][r*256+k] = W[layer][r][k][n]  (bf16, B^T layout for GEMM)
__global__ __launch_bounds__(256) void prep_w_kernel(
    const float* __restrict__ W1, const float* __restrict__ W2,
    unsigned short* __restrict__ wt1, unsigned short* __restrict__ wt2) {
  int t = blockIdx.x * 256 + threadIdx.x;   // 2*3*256*256
  int lay = t / (NR * NF * NF);
  int rem = t % (NR * NF * NF);
  int r = rem / (NF * NF);
  int k = (rem / NF) % NF;
  int n = rem % NF;
  const float* W = lay ? W2 : W1;
  unsigned short* wt = lay ? wt2 : wt1;
  wt[(size_t)n * NK + r * NF + k] = f2bfu(W[((size_t)r * NF + k) * NF + n]);
}

__global__ __launch_bounds__(256) void prep_bias_kernel(
    const float* __restrict__ b1, const float* __restrict__ b2,
    float* __restrict__ bs1, float* __restrict__ bs2) {
  int t = blockIdx.x * 256 + threadIdx.x;   // 512
  if (t < 2 * NF) {
    int lay = t / NF, n = t % NF;
    const float* b = lay ? b2 : b1;
    float* bs = lay ? bs2 : bs1;
    bs[n] = b[n] + b[NF + n] + b[2 * NF + n];
  }
}

__global__ __launch_bounds__(256) void cast_kernel(
    const float* __restrict__ in, unsigned short* __restrict__ out, int n4) {
  int t = blockIdx.x * 256 + threadIdx.x;
  if (t < n4) {
    floatx4 v = *(const floatx4*)&in[(size_t)t * 4];
    ushortx4 o;
    o.x = f2bfu(v.x); o.y = f2bfu(v.y); o.z = f2bfu(v.z); o.w = f2bfu(v.w);
    *(ushortx4*)&out[(size_t)t * 4] = o;
  }
}

// ---------------- SpMM: one wave per (node, relation), pull via CSR ----------------

__global__ __launch_bounds__(256) void spmm_kernel(
    const unsigned short* __restrict__ x,   // [NN][256] bf16
    const int* __restrict__ rowptr, const int* __restrict__ csr_src,
    const float* __restrict__ csr_w, const float* __restrict__ n_dst,
    unsigned short* __restrict__ agg) {     // [NN][768] bf16
  int wid = threadIdx.x >> 6, l = threadIdx.x & 63;
  int r = blockIdx.y;
  int v = blockIdx.x * 4 + wid;
  if (v >= NN) return;
  int e0 = rowptr[(size_t)r * (NN + 1) + v];
  int e1 = rowptr[(size_t)r * (NN + 1) + v + 1];
  const int* cs = csr_src + (size_t)r * NE;
  const float* cw = csr_w + (size_t)r * NE;
  float a0 = 0.f, a1 = 0.f, a2 = 0.f, a3 = 0.f;
  for (int e = e0; e < e1; ++e) {
    int s = cs[e];
    float w = cw[e];
    ushortx4 xv = *(const ushortx4*)&x[(size_t)s * NF + l * 4];
    a0 += w * bfu2f(xv.x);
    a1 += w * bfu2f(xv.y);
    a2 += w * bfu2f(xv.z);
    a3 += w * bfu2f(xv.w);
  }
  float nd = n_dst[r * NN + v];
  ushortx4 o;
  o.x = f2bfu(a0 * nd); o.y = f2bfu(a1 * nd);
  o.z = f2bfu(a2 * nd); o.w = f2bfu(a3 * nd);
  *(ushortx4*)&agg[(size_t)v * NK + r * NF + l * 4] = o;
}

// ---------------- GEMM: [M,768] @ [768,256] bf16 MFMA (m97 128x128 structure) ----------------

__global__ __launch_bounds__(256) void gemm_kernel(
    const unsigned short* __restrict__ A,    // [M][768] bf16
    const unsigned short* __restrict__ Bt,   // [256][768] bf16 (B^T)
    const float* __restrict__ bias,          // [256]
    unsigned short* __restrict__ C,          // [M][256] bf16
    int M, int relu) {
  __shared__ unsigned short ldsA[128 * 32];
  __shared__ unsigned short ldsB[128 * 32];
  const int tid = threadIdx.x;
  const int l = tid & 63, wid = tid >> 6;
  const int wr = wid >> 1, wc = wid & 1;
  const int row0 = blockIdx.x * 128, col0 = blockIdx.y * 128;

  floatx4 acc[4][4];
#pragma unroll
  for (int i = 0; i < 4; ++i)
#pragma unroll
    for (int j = 0; j < 4; ++j)
#pragma unroll
      for (int q = 0; q < 4; ++q) acc[i][j][q] = 0.f;

  const int srow = l >> 2;          // staging: row within 16-row chunk
  const int skc = (l & 3) * 8;      // staging: k offset (8 bf16 = 16B)
  const int fr = l & 15, fk = (l >> 4) * 8;

  for (int kt = 0; kt < NK / 32; ++kt) {
    const int k0 = kt * 32;
#pragma unroll
    for (int it = 0; it < 2; ++it) {
      int ci = it * 4 + wid;                     // chunk 0..7 (16 rows each)
      int arow = row0 + ci * 16 + srow;
      if (arow >= M) arow = M - 1;               // clamp, masked at store
      gload16(A + (size_t)arow * NK + k0 + skc, &ldsA[ci * 512 + l * 8]);
      int brow = col0 + ci * 16 + srow;          // N=256 exact
      gload16(Bt + (size_t)brow * NK + k0 + skc, &ldsB[ci * 512 + l * 8]);
    }
    asm volatile("s_waitcnt vmcnt(0)" ::: "memory");
    __syncthreads();

    short8 af[4], bf[4];
#pragma unroll
    for (int m = 0; m < 4; ++m)
      af[m] = *(const short8*)&ldsA[(wr * 64 + m * 16 + fr) * 32 + fk];
#pragma unroll
    for (int n = 0; n < 4; ++n)
      bf[n] = *(const short8*)&ldsB[(wc * 64 + n * 16 + fr) * 32 + fk];
#pragma unroll
    for (int m = 0; m < 4; ++m)
#pragma unroll
      for (int n = 0; n < 4; ++n)
        acc[m][n] = __builtin_amdgcn_mfma_f32_16x16x32_bf16(af[m], bf[n], acc[m][n], 0, 0, 0);
    __syncthreads();
  }

  const int fq = l >> 4;
#pragma unroll
  for (int m = 0; m < 4; ++m) {
#pragma unroll
    for (int n = 0; n < 4; ++n) {
      int col = col0 + wc * 64 + n * 16 + fr;
      float bv = bias[col];
#pragma unroll
      for (int q = 0; q < 4; ++q) {
        int row = row0 + wr * 64 + m * 16 + fq * 4 + q;
        if (row < M) {
          float vv = acc[m][n][q] + bv;
          if (relu) vv = fmaxf(vv, 0.f);
          C[(size_t)row * NF + col] = f2bfu(vv);
        }
      }
    }
  }
}

// ---------------- pooling ----------------

__global__ __launch_bounds__(256) void pool_kernel(
    const unsigned short* __restrict__ h2, const int* __restrict__ gid,
    float* __restrict__ poolsum) {
  int c = threadIdx.x;                 // column 0..255
  int v0 = blockIdx.x * 256;
  int vend = min(v0 + 256, NN);
  float acc = 0.f;
  int curg = -1;
  for (int v = v0; v < vend; ++v) {
    int g = gid[v];                    // sorted -> few runs per chunk
    if (g != curg) {
      if (curg >= 0) atomicAdd(&poolsum[curg * NF + c], acc);
      curg = g; acc = 0.f;
    }
    acc += bfu2f(h2[(size_t)v * NF + c]);
  }
  if (curg >= 0) atomicAdd(&poolsum[curg * NF + c], acc);
}

__global__ __launch_bounds__(256) void final_kernel(
    const float* __restrict__ poolsum, const int* __restrict__ gcount,
    float* __restrict__ out) {
  int g = blockIdx.x, c = threadIdx.x;
  out[g * NF + c] = poolsum[g * NF + c] / fmaxf((float)gcount[g], 1.f);
}

// ---------------- launch ----------------

extern "C" void kernel_launch(void* const* d_in, const int* in_sizes, int n_in,
                              void* d_out, int out_size, void* d_ws, size_t ws_size,
                              hipStream_t stream) {
  const float* feat = (const float*)d_in[0];
  const int* src = (const int*)d_in[1];
  const int* dst = (const int*)d_in[2];
  const int* gid = (const int*)d_in[3];
  const float* W1 = (const float*)d_in[4];
  const float* b1 = (const float*)d_in[5];
  const float* W2 = (const float*)d_in[6];
  const float* b2 = (const float*)d_in[7];
  float* out = (float*)d_out;

  char* ws = (char*)d_ws;
  size_t off = 0;
  auto alloc = [&](size_t bytes) -> void* {
    void* p = ws + off;
    off = (off + bytes + 255) & ~(size_t)255;
    return p;
  };

  // zero-initialized block (single memset)
  int* deg_out = (int*)alloc((size_t)NR * NN * 4);
  int* deg_in  = (int*)alloc((size_t)NR * NN * 4);
  int* cursor  = (int*)alloc((size_t)NR * NN * 4);
  float* poolsum = (float*)alloc((size_t)NG * NF * 4);
  size_t zero_bytes = off;

  int* gcount  = (int*)alloc((size_t)NG * 4);
  int* blocksum = (int*)alloc((size_t)NR * SCAN_NB * 4);
  float* n_src = (float*)alloc((size_t)NR * NN * 4);
  float* n_dst = (float*)alloc((size_t)NR * NN * 4);
  int* rowptr  = (int*)alloc((size_t)NR * (NN + 1) * 4);
  int* csr_src = (int*)alloc((size_t)NR * NE * 4);
  float* csr_w = (float*)alloc((size_t)NR * NE * 4);
  unsigned short* wt1 = (unsigned short*)alloc((size_t)NF * NK * 2);
  unsigned short* wt2 = (unsigned short*)alloc((size_t)NF * NK * 2);
  float* bs1 = (float*)alloc(NF * 4);
  float* bs2 = (float*)alloc(NF * 4);
  unsigned short* featbf = (unsigned short*)alloc((size_t)NN * NF * 2);
  unsigned short* h1 = (unsigned short*)alloc((size_t)NN * NF * 2);
  unsigned short* h2 = (unsigned short*)alloc((size_t)NN * NF * 2);
  unsigned short* agg = (unsigned short*)alloc((size_t)NN * NK * 2);
  (void)ws_size; (void)in_sizes; (void)n_in; (void)out_size;

  hipMemsetAsync(d_ws, 0, zero_bytes, stream);

  dim3 eg((NE + 255) / 256, NR);
  degree_kernel<<<eg, 256, 0, stream>>>(src, dst, deg_out, deg_in);
  gcount_kernel<<<1, 128, 0, stream>>>(gid, gcount);
  norm_kernel<<<(NR * NN + 255) / 256, 256, 0, stream>>>(deg_out, deg_in, n_src, n_dst);
  scan_phaseA<<<dim3(SCAN_NB, NR), 256, 0, stream>>>(deg_in, blocksum);
  scan_phaseB<<<NR, 128, 0, stream>>>(blocksum, rowptr);
  scan_phaseC<<<dim3(SCAN_NB, NR), 256, 0, stream>>>(deg_in, blocksum, rowptr);
  scatter_kernel<<<eg, 256, 0, stream>>>(src, dst, rowptr, cursor, n_src, csr_src, csr_w);

  prep_w_kernel<<<(2 * NR * NF * NF) / 256, 256, 0, stream>>>(W1, W2, wt1, wt2);
  prep_bias_kernel<<<2, 256, 0, stream>>>(b1, b2, bs1, bs2);
  cast_kernel<<<(NN * NF / 4 + 255) / 256, 256, 0, stream>>>(feat, featbf, NN * NF / 4);

  dim3 sg((NN + 3) / 4, NR);
  // layer 1
  spmm_kernel<<<sg, 256, 0, stream>>>(featbf, rowptr, csr_src, csr_w, n_dst, agg);
  gemm_kernel<<<dim3((NN + 127) / 128, 2), 256, 0, stream>>>(agg, wt1, bs1, h1, NN, 1);
  // layer 2
  spmm_kernel<<<sg, 256, 0, stream>>>(h1, rowptr, csr_src, csr_w, n_dst, agg);
  gemm_kernel<<<dim3((NN + 127) / 128, 2), 256, 0, stream>>>(agg, wt2, bs2, h2, NN, 0);
  // pooling
  pool_kernel<<<(NN + 255) / 256, 256, 0, stream>>>(h2, gid, poolsum);
  final_kernel<<<NG, 256, 0, stream>>>(poolsum, gcount, out);
}

// Round 4
// 739.962 us; speedup vs baseline: 1.7266x; 1.1373x over previous
//
#include <hip/hip_runtime.h>
#include <stdint.h>

#define NN 100000   // nodes
#define NE 400000   // edges per relation
#define NR 3        // relations
#define NF 256      // feature dim
#define NK 768      // NR*NF concatenated K
#define NG 128      // graphs
#define SCAN_NB ((NN + 1023) / 1024)   // 98 chunks of 1024

typedef __attribute__((ext_vector_type(4))) unsigned short ushortx4;
typedef __attribute__((ext_vector_type(8))) short short8;
typedef __attribute__((ext_vector_type(4))) float floatx4;

static __device__ __forceinline__ unsigned short f2bfu(float f) {
  union { float f; uint32_t u; } c; c.f = f;
  uint32_t x = c.u;
  uint32_t r = (x + 0x7fffu + ((x >> 16) & 1u)) >> 16;
  return (unsigned short)r;
}
static __device__ __forceinline__ float bfu2f(unsigned short u) {
  union { uint32_t u; float f; } c; c.u = ((uint32_t)u) << 16;
  return c.f;
}

static __device__ __forceinline__ void gload16(const void* g, void* l) {
  __builtin_amdgcn_global_load_lds(
      (const __attribute__((address_space(1))) uint32_t*)g,
      (__attribute__((address_space(3))) uint32_t*)l, 16, 0, 0);
}

// ---------------- graph preprocessing ----------------

__global__ __launch_bounds__(256) void degree_kernel(
    const int* __restrict__ src, const int* __restrict__ dst,
    int* __restrict__ deg_out, int* __restrict__ deg_in) {
  int t = blockIdx.x * 256 + threadIdx.x;
  int r = blockIdx.y;
  if (t < NE) {
    atomicAdd(&deg_out[r * NN + src[r * NE + t]], 1);
    atomicAdd(&deg_in[r * NN + dst[r * NE + t]], 1);
  }
}

// gid is sorted: count[g] = lb(g+1) - lb(g) via binary search. No atomics.
__global__ __launch_bounds__(128) void gcount_kernel(
    const int* __restrict__ gid, int* __restrict__ gcount) {
  int g = threadIdx.x;  // 0..127
  int lo = 0, hi = NN;
  while (lo < hi) { int mid = (lo + hi) >> 1; if (gid[mid] < g) lo = mid + 1; else hi = mid; }
  int a = lo;
  lo = 0; hi = NN;
  while (lo < hi) { int mid = (lo + hi) >> 1; if (gid[mid] < g + 1) lo = mid + 1; else hi = mid; }
  gcount[g] = lo - a;
}

__global__ __launch_bounds__(256) void norm_kernel(
    const int* __restrict__ deg_out, const int* __restrict__ deg_in,
    float* __restrict__ n_src, float* __restrict__ n_dst) {
  int t = blockIdx.x * 256 + threadIdx.x;
  if (t < NR * NN) {
    int dof = deg_out[t], din = deg_in[t];
    n_src[t] = dof > 0 ? rsqrtf((float)dof) : 0.f;
    n_dst[t] = din > 0 ? rsqrtf((float)din) : 0.f;
  }
}

// ---- multi-block exclusive scan of deg_in -> rowptr (3 phases) ----

__global__ __launch_bounds__(256) void scan_phaseA(
    const int* __restrict__ deg_in, int* __restrict__ blocksum) {
  int r = blockIdx.y, b = blockIdx.x, tid = threadIdx.x;
  const int* deg = deg_in + (size_t)r * NN;
  int base = b * 1024 + tid * 4;
  int s = 0;
#pragma unroll
  for (int i = 0; i < 4; ++i) { int idx = base + i; if (idx < NN) s += deg[idx]; }
  __shared__ int red[256];
  red[tid] = s; __syncthreads();
  for (int off = 128; off > 0; off >>= 1) {
    if (tid < off) red[tid] += red[tid + off];
    __syncthreads();
  }
  if (tid == 0) blocksum[r * SCAN_NB + b] = red[0];
}

__global__ __launch_bounds__(128) void scan_phaseB(
    int* __restrict__ blocksum, int* __restrict__ rowptr) {
  int r = blockIdx.x, tid = threadIdx.x;
  int* bs = blocksum + r * SCAN_NB;
  __shared__ int buf[128];
  int v = (tid < SCAN_NB) ? bs[tid] : 0;
  buf[tid] = v; __syncthreads();
  for (int off = 1; off < 128; off <<= 1) {
    int t = (tid >= off) ? buf[tid - off] : 0;
    __syncthreads();
    buf[tid] += t;
    __syncthreads();
  }
  if (tid < SCAN_NB) bs[tid] = buf[tid] - v;   // exclusive chunk offset
  if (tid == 127) rowptr[(size_t)r * (NN + 1) + NN] = buf[127];
}

__global__ __launch_bounds__(256) void scan_phaseC(
    const int* __restrict__ deg_in, const int* __restrict__ blocksum,
    int* __restrict__ rowptr) {
  int r = blockIdx.y, b = blockIdx.x, tid = threadIdx.x;
  const int* deg = deg_in + (size_t)r * NN;
  int* rp = rowptr + (size_t)r * (NN + 1);
  int base = b * 1024 + tid * 4;
  int v[4]; int s = 0;
#pragma unroll
  for (int i = 0; i < 4; ++i) { int idx = base + i; v[i] = (idx < NN) ? deg[idx] : 0; s += v[i]; }
  __shared__ int buf[256];
  buf[tid] = s; __syncthreads();
  for (int off = 1; off < 256; off <<= 1) {
    int t = (tid >= off) ? buf[tid - off] : 0;
    __syncthreads();
    buf[tid] += t;
    __syncthreads();
  }
  int excl = buf[tid] - s + blocksum[r * SCAN_NB + b];
#pragma unroll
  for (int i = 0; i < 4; ++i) {
    int idx = base + i;
    if (idx < NN) rp[idx] = excl;
    excl += v[i];
  }
}

__global__ __launch_bounds__(256) void scatter_kernel(
    const int* __restrict__ src, const int* __restrict__ dst,
    const int* __restrict__ rowptr, int* __restrict__ cursor,
    const float* __restrict__ n_src,
    int* __restrict__ csr_src, float* __restrict__ csr_w) {
  int t = blockIdx.x * 256 + threadIdx.x;
  int r = blockIdx.y;
  if (t < NE) {
    int s = src[r * NE + t], v = dst[r * NE + t];
    int pos = atomicAdd(&cursor[r * NN + v], 1);
    int idx = r * NE + rowptr[(size_t)r * (NN + 1) + v] + pos;
    csr_src[idx] = s;
    csr_w[idx] = n_src[r * NN + s];
  }
}

// ---------------- weight / feature prep ----------------

// wt[layer][n][r*256+k] = W[layer][r][k][n]  (bf16, B^T layout for GEMM)
__global__ __launch_bounds__(256) void prep_w_kernel(
    const float* __restrict__ W1, const float* __restrict__ W2,
    unsigned short* __restrict__ wt1, unsigned short* __restrict__ wt2) {
  int t = blockIdx.x * 256 + threadIdx.x;   // 2*3*256*256
  int lay = t / (NR * NF * NF);
  int rem = t % (NR * NF * NF);
  int r = rem / (NF * NF);
  int k = (rem / NF) % NF;
  int n = rem % NF;
  const float* W = lay ? W2 : W1;
  unsigned short* wt = lay ? wt2 : wt1;
  wt[(size_t)n * NK + r * NF + k] = f2bfu(W[((size_t)r * NF + k) * NF + n]);
}

__global__ __launch_bounds__(256) void prep_bias_kernel(
    const float* __restrict__ b1, const float* __restrict__ b2,
    float* __restrict__ bs1, float* __restrict__ bs2) {
  int t = blockIdx.x * 256 + threadIdx.x;   // 512
  if (t < 2 * NF) {
    int lay = t / NF, n = t % NF;
    const float* b = lay ? b2 : b1;
    float* bs = lay ? bs2 : bs1;
    bs[n] = b[n] + b[NF + n] + b[2 * NF + n];
  }
}

__global__ __launch_bounds__(256) void cast_kernel(
    const float* __restrict__ in, unsigned short* __restrict__ out, int n4) {
  int t = blockIdx.x * 256 + threadIdx.x;
  if (t < n4) {
    floatx4 v = *(const floatx4*)&in[(size_t)t * 4];
    ushortx4 o;
    o.x = f2bfu(v.x); o.y = f2bfu(v.y); o.z = f2bfu(v.z); o.w = f2bfu(v.w);
    *(ushortx4*)&out[(size_t)t * 4] = o;
  }
}

// ---------------- SpMM: one wave per (node, relation), pull via CSR ----------------
// Unroll-4: batch the 4 index loads, then 4 INDEPENDENT row gathers -> 4x MLP
// on the dependent-load critical path.

__global__ __launch_bounds__(256) void spmm_kernel(
    const unsigned short* __restrict__ x,   // [NN][256] bf16
    const int* __restrict__ rowptr, const int* __restrict__ csr_src,
    const float* __restrict__ csr_w, const float* __restrict__ n_dst,
    unsigned short* __restrict__ agg) {     // [NN][768] bf16
  int wid = threadIdx.x >> 6, l = threadIdx.x & 63;
  int r = blockIdx.y;
  int v = blockIdx.x * 4 + wid;
  if (v >= NN) return;
  int e0 = rowptr[(size_t)r * (NN + 1) + v];
  int e1 = rowptr[(size_t)r * (NN + 1) + v + 1];
  const int* cs = csr_src + (size_t)r * NE;
  const float* cw = csr_w + (size_t)r * NE;
  float a0 = 0.f, a1 = 0.f, a2 = 0.f, a3 = 0.f;
  int e = e0;
  for (; e + 4 <= e1; e += 4) {
    int s0 = cs[e], s1 = cs[e + 1], s2 = cs[e + 2], s3 = cs[e + 3];
    float w0 = cw[e], w1 = cw[e + 1], w2 = cw[e + 2], w3 = cw[e + 3];
    ushortx4 x0 = *(const ushortx4*)&x[(size_t)s0 * NF + l * 4];
    ushortx4 x1 = *(const ushortx4*)&x[(size_t)s1 * NF + l * 4];
    ushortx4 x2 = *(const ushortx4*)&x[(size_t)s2 * NF + l * 4];
    ushortx4 x3 = *(const ushortx4*)&x[(size_t)s3 * NF + l * 4];
    a0 += w0 * bfu2f(x0.x) + w1 * bfu2f(x1.x) + w2 * bfu2f(x2.x) + w3 * bfu2f(x3.x);
    a1 += w0 * bfu2f(x0.y) + w1 * bfu2f(x1.y) + w2 * bfu2f(x2.y) + w3 * bfu2f(x3.y);
    a2 += w0 * bfu2f(x0.z) + w1 * bfu2f(x1.z) + w2 * bfu2f(x2.z) + w3 * bfu2f(x3.z);
    a3 += w0 * bfu2f(x0.w) + w1 * bfu2f(x1.w) + w2 * bfu2f(x2.w) + w3 * bfu2f(x3.w);
  }
  for (; e < e1; ++e) {
    int s = cs[e];
    float w = cw[e];
    ushortx4 xv = *(const ushortx4*)&x[(size_t)s * NF + l * 4];
    a0 += w * bfu2f(xv.x);
    a1 += w * bfu2f(xv.y);
    a2 += w * bfu2f(xv.z);
    a3 += w * bfu2f(xv.w);
  }
  float nd = n_dst[r * NN + v];
  ushortx4 o;
  o.x = f2bfu(a0 * nd); o.y = f2bfu(a1 * nd);
  o.z = f2bfu(a2 * nd); o.w = f2bfu(a3 * nd);
  *(ushortx4*)&agg[(size_t)v * NK + r * NF + l * 4] = o;
}

// ---------------- GEMM: [M,768] @ [768,256], BN=256 full width ----------------
// Block computes 128 rows x 256 cols; A read exactly once (no col-block re-read).
// 4 waves, each 128x64: acc[8][4]. LDS: A 8KB + B 16KB.

__global__ __launch_bounds__(256, 2) void gemm_kernel(
    const unsigned short* __restrict__ A,    // [M][768] bf16
    const unsigned short* __restrict__ Bt,   // [256][768] bf16 (B^T: [col][K])
    const float* __restrict__ bias,          // [256]
    unsigned short* __restrict__ C,          // [M][256] bf16
    int M, int relu) {
  __shared__ unsigned short ldsA[128 * 32];   // [row][32]
  __shared__ unsigned short ldsB[256 * 32];   // [col][32]
  const int tid = threadIdx.x;
  const int l = tid & 63, wid = tid >> 6;
  const int row0 = blockIdx.x * 128;
  const int c0 = wid * 64;                    // wave's 64-col strip

  floatx4 acc[8][4];
#pragma unroll
  for (int i = 0; i < 8; ++i)
#pragma unroll
    for (int j = 0; j < 4; ++j)
#pragma unroll
      for (int q = 0; q < 4; ++q) acc[i][j][q] = 0.f;

  const int fr = l & 15, fk = (l >> 4) * 8;

  for (int kt = 0; kt < NK / 32; ++kt) {
    const int k0 = kt * 32;
    // stage A: 512 x 16B units; wave-linear LDS dest (base + l*16)
    {
      int u = wid * 64 + l;                   // pass 0: units 0..255
      int arow = row0 + (u >> 2);
      if (arow >= M) arow = M - 1;
      gload16(A + (size_t)arow * NK + k0 + (u & 3) * 8, &ldsA[u * 8]);
      u += 256;                               // pass 1: units 256..511
      arow = row0 + (u >> 2);
      if (arow >= M) arow = M - 1;
      gload16(A + (size_t)arow * NK + k0 + (u & 3) * 8, &ldsA[u * 8]);
    }
    // stage B: 1024 x 16B units (256 cols x 64B)
#pragma unroll
    for (int p = 0; p < 4; ++p) {
      int u = p * 256 + wid * 64 + l;
      int col = u >> 2;
      gload16(Bt + (size_t)col * NK + k0 + (u & 3) * 8, &ldsB[u * 8]);
    }
    asm volatile("s_waitcnt vmcnt(0)" ::: "memory");
    __syncthreads();

    short8 af[8], bf[4];
#pragma unroll
    for (int m = 0; m < 8; ++m)
      af[m] = *(const short8*)&ldsA[(m * 16 + fr) * 32 + fk];
#pragma unroll
    for (int n = 0; n < 4; ++n)
      bf[n] = *(const short8*)&ldsB[(c0 + n * 16 + fr) * 32 + fk];
#pragma unroll
    for (int m = 0; m < 8; ++m)
#pragma unroll
      for (int n = 0; n < 4; ++n)
        acc[m][n] = __builtin_amdgcn_mfma_f32_16x16x32_bf16(af[m], bf[n], acc[m][n], 0, 0, 0);
    __syncthreads();
  }

  const int fq = l >> 4;
#pragma unroll
  for (int m = 0; m < 8; ++m) {
#pragma unroll
    for (int n = 0; n < 4; ++n) {
      int col = c0 + n * 16 + fr;
      float bv = bias[col];
#pragma unroll
      for (int q = 0; q < 4; ++q) {
        int row = row0 + m * 16 + fq * 4 + q;
        if (row < M) {
          float vv = acc[m][n][q] + bv;
          if (relu) vv = fmaxf(vv, 0.f);
          C[(size_t)row * NF + col] = f2bfu(vv);
        }
      }
    }
  }
}

// ---------------- pooling ----------------

__global__ __launch_bounds__(256) void pool_kernel(
    const unsigned short* __restrict__ h2, const int* __restrict__ gid,
    float* __restrict__ poolsum) {
  int c = threadIdx.x;                 // column 0..255
  int v0 = blockIdx.x * 256;
  int vend = min(v0 + 256, NN);
  float acc = 0.f;
  int curg = -1;
  for (int v = v0; v < vend; ++v) {
    int g = gid[v];                    // sorted -> few runs per chunk
    if (g != curg) {
      if (curg >= 0) atomicAdd(&poolsum[curg * NF + c], acc);
      curg = g; acc = 0.f;
    }
    acc += bfu2f(h2[(size_t)v * NF + c]);
  }
  if (curg >= 0) atomicAdd(&poolsum[curg * NF + c], acc);
}

__global__ __launch_bounds__(256) void final_kernel(
    const float* __restrict__ poolsum, const int* __restrict__ gcount,
    float* __restrict__ out) {
  int g = blockIdx.x, c = threadIdx.x;
  out[g * NF + c] = poolsum[g * NF + c] / fmaxf((float)gcount[g], 1.f);
}

// ---------------- launch ----------------

extern "C" void kernel_launch(void* const* d_in, const int* in_sizes, int n_in,
                              void* d_out, int out_size, void* d_ws, size_t ws_size,
                              hipStream_t stream) {
  const float* feat = (const float*)d_in[0];
  const int* src = (const int*)d_in[1];
  const int* dst = (const int*)d_in[2];
  const int* gid = (const int*)d_in[3];
  const float* W1 = (const float*)d_in[4];
  const float* b1 = (const float*)d_in[5];
  const float* W2 = (const float*)d_in[6];
  const float* b2 = (const float*)d_in[7];
  float* out = (float*)d_out;

  char* ws = (char*)d_ws;
  size_t off = 0;
  auto alloc = [&](size_t bytes) -> void* {
    void* p = ws + off;
    off = (off + bytes + 255) & ~(size_t)255;
    return p;
  };

  // zero-initialized block (single memset)
  int* deg_out = (int*)alloc((size_t)NR * NN * 4);
  int* deg_in  = (int*)alloc((size_t)NR * NN * 4);
  int* cursor  = (int*)alloc((size_t)NR * NN * 4);
  float* poolsum = (float*)alloc((size_t)NG * NF * 4);
  size_t zero_bytes = off;

  int* gcount  = (int*)alloc((size_t)NG * 4);
  int* blocksum = (int*)alloc((size_t)NR * SCAN_NB * 4);
  float* n_src = (float*)alloc((size_t)NR * NN * 4);
  float* n_dst = (float*)alloc((size_t)NR * NN * 4);
  int* rowptr  = (int*)alloc((size_t)NR * (NN + 1) * 4);
  int* csr_src = (int*)alloc((size_t)NR * NE * 4);
  float* csr_w = (float*)alloc((size_t)NR * NE * 4);
  unsigned short* wt1 = (unsigned short*)alloc((size_t)NF * NK * 2);
  unsigned short* wt2 = (unsigned short*)alloc((size_t)NF * NK * 2);
  float* bs1 = (float*)alloc(NF * 4);
  float* bs2 = (float*)alloc(NF * 4);
  unsigned short* featbf = (unsigned short*)alloc((size_t)NN * NF * 2);
  unsigned short* h1 = (unsigned short*)alloc((size_t)NN * NF * 2);
  unsigned short* h2 = (unsigned short*)alloc((size_t)NN * NF * 2);
  unsigned short* agg = (unsigned short*)alloc((size_t)NN * NK * 2);
  (void)ws_size; (void)in_sizes; (void)n_in; (void)out_size;

  hipMemsetAsync(d_ws, 0, zero_bytes, stream);

  dim3 eg((NE + 255) / 256, NR);
  degree_kernel<<<eg, 256, 0, stream>>>(src, dst, deg_out, deg_in);
  gcount_kernel<<<1, 128, 0, stream>>>(gid, gcount);
  norm_kernel<<<(NR * NN + 255) / 256, 256, 0, stream>>>(deg_out, deg_in, n_src, n_dst);
  scan_phaseA<<<dim3(SCAN_NB, NR), 256, 0, stream>>>(deg_in, blocksum);
  scan_phaseB<<<NR, 128, 0, stream>>>(blocksum, rowptr);
  scan_phaseC<<<dim3(SCAN_NB, NR), 256, 0, stream>>>(deg_in, blocksum, rowptr);
  scatter_kernel<<<eg, 256, 0, stream>>>(src, dst, rowptr, cursor, n_src, csr_src, csr_w);

  prep_w_kernel<<<(2 * NR * NF * NF) / 256, 256, 0, stream>>>(W1, W2, wt1, wt2);
  prep_bias_kernel<<<2, 256, 0, stream>>>(b1, b2, bs1, bs2);
  cast_kernel<<<(NN * NF / 4 + 255) / 256, 256, 0, stream>>>(feat, featbf, NN * NF / 4);

  dim3 sg((NN + 3) / 4, NR);
  // layer 1
  spmm_kernel<<<sg, 256, 0, stream>>>(featbf, rowptr, csr_src, csr_w, n_dst, agg);
  gemm_kernel<<<(NN + 127) / 128, 256, 0, stream>>>(agg, wt1, bs1, h1, NN, 1);
  // layer 2
  spmm_kernel<<<sg, 256, 0, stream>>>(h1, rowptr, csr_src, csr_w, n_dst, agg);
  gemm_kernel<<<(NN + 127) / 128, 256, 0, stream>>>(agg, wt2, bs2, h2, NN, 0);
  // pooling
  pool_kernel<<<(NN + 255) / 256, 256, 0, stream>>>(h2, gid, poolsum);
  final_kernel<<<NG, 256, 0, stream>>>(poolsum, gcount, out);
}

// Round 5
// 718.357 us; speedup vs baseline: 1.7785x; 1.0301x over previous
//
#include <hip/hip_runtime.h>
#include <stdint.h>

#define NN 100000   // nodes
#define NE 400000   // edges per relation
#define NR 3        // relations
#define NF 256      // feature dim
#define NK 768      // NR*NF concatenated K
#define NG 128      // graphs
#define SCAN_NB ((NN + 1023) / 1024)   // 98 chunks of 1024

typedef __attribute__((ext_vector_type(4))) unsigned short ushortx4;
typedef __attribute__((ext_vector_type(8))) unsigned short ushortx8;
typedef __attribute__((ext_vector_type(8))) short short8;
typedef __attribute__((ext_vector_type(4))) float floatx4;

static __device__ __forceinline__ unsigned short f2bfu(float f) {
  union { float f; uint32_t u; } c; c.f = f;
  uint32_t x = c.u;
  uint32_t r = (x + 0x7fffu + ((x >> 16) & 1u)) >> 16;
  return (unsigned short)r;
}
static __device__ __forceinline__ float bfu2f(unsigned short u) {
  union { uint32_t u; float f; } c; c.u = ((uint32_t)u) << 16;
  return c.f;
}

static __device__ __forceinline__ void gload16(const void* g, void* l) {
  __builtin_amdgcn_global_load_lds(
      (const __attribute__((address_space(1))) uint32_t*)g,
      (__attribute__((address_space(3))) uint32_t*)l, 16, 0, 0);
}

// ---------------- graph preprocessing ----------------

__global__ __launch_bounds__(256) void degree_kernel(
    const int* __restrict__ src, const int* __restrict__ dst,
    int* __restrict__ deg_out, int* __restrict__ deg_in) {
  int t = blockIdx.x * 256 + threadIdx.x;
  int r = blockIdx.y;
  if (t < NE) {
    atomicAdd(&deg_out[r * NN + src[r * NE + t]], 1);
    atomicAdd(&deg_in[r * NN + dst[r * NE + t]], 1);
  }
}

// gid is sorted: count[g] = lb(g+1) - lb(g) via binary search. No atomics.
__global__ __launch_bounds__(128) void gcount_kernel(
    const int* __restrict__ gid, int* __restrict__ gcount) {
  int g = threadIdx.x;  // 0..127
  int lo = 0, hi = NN;
  while (lo < hi) { int mid = (lo + hi) >> 1; if (gid[mid] < g) lo = mid + 1; else hi = mid; }
  int a = lo;
  lo = 0; hi = NN;
  while (lo < hi) { int mid = (lo + hi) >> 1; if (gid[mid] < g + 1) lo = mid + 1; else hi = mid; }
  gcount[g] = lo - a;
}

__global__ __launch_bounds__(256) void norm_kernel(
    const int* __restrict__ deg_out, const int* __restrict__ deg_in,
    float* __restrict__ n_src, float* __restrict__ n_dst) {
  int t = blockIdx.x * 256 + threadIdx.x;
  if (t < NR * NN) {
    int dof = deg_out[t], din = deg_in[t];
    n_src[t] = dof > 0 ? rsqrtf((float)dof) : 0.f;
    n_dst[t] = din > 0 ? rsqrtf((float)din) : 0.f;
  }
}

// ---- multi-block exclusive scan of deg_in -> rowptr (3 phases) ----

__global__ __launch_bounds__(256) void scan_phaseA(
    const int* __restrict__ deg_in, int* __restrict__ blocksum) {
  int r = blockIdx.y, b = blockIdx.x, tid = threadIdx.x;
  const int* deg = deg_in + (size_t)r * NN;
  int base = b * 1024 + tid * 4;
  int s = 0;
#pragma unroll
  for (int i = 0; i < 4; ++i) { int idx = base + i; if (idx < NN) s += deg[idx]; }
  __shared__ int red[256];
  red[tid] = s; __syncthreads();
  for (int off = 128; off > 0; off >>= 1) {
    if (tid < off) red[tid] += red[tid + off];
    __syncthreads();
  }
  if (tid == 0) blocksum[r * SCAN_NB + b] = red[0];
}

__global__ __launch_bounds__(128) void scan_phaseB(
    int* __restrict__ blocksum, int* __restrict__ rowptr) {
  int r = blockIdx.x, tid = threadIdx.x;
  int* bs = blocksum + r * SCAN_NB;
  __shared__ int buf[128];
  int v = (tid < SCAN_NB) ? bs[tid] : 0;
  buf[tid] = v; __syncthreads();
  for (int off = 1; off < 128; off <<= 1) {
    int t = (tid >= off) ? buf[tid - off] : 0;
    __syncthreads();
    buf[tid] += t;
    __syncthreads();
  }
  if (tid < SCAN_NB) bs[tid] = buf[tid] - v;   // exclusive chunk offset
  if (tid == 127) rowptr[(size_t)r * (NN + 1) + NN] = buf[127];
}

__global__ __launch_bounds__(256) void scan_phaseC(
    const int* __restrict__ deg_in, const int* __restrict__ blocksum,
    int* __restrict__ rowptr) {
  int r = blockIdx.y, b = blockIdx.x, tid = threadIdx.x;
  const int* deg = deg_in + (size_t)r * NN;
  int* rp = rowptr + (size_t)r * (NN + 1);
  int base = b * 1024 + tid * 4;
  int v[4]; int s = 0;
#pragma unroll
  for (int i = 0; i < 4; ++i) { int idx = base + i; v[i] = (idx < NN) ? deg[idx] : 0; s += v[i]; }
  __shared__ int buf[256];
  buf[tid] = s; __syncthreads();
  for (int off = 1; off < 256; off <<= 1) {
    int t = (tid >= off) ? buf[tid - off] : 0;
    __syncthreads();
    buf[tid] += t;
    __syncthreads();
  }
  int excl = buf[tid] - s + blocksum[r * SCAN_NB + b];
#pragma unroll
  for (int i = 0; i < 4; ++i) {
    int idx = base + i;
    if (idx < NN) rp[idx] = excl;
    excl += v[i];
  }
}

// csr_e[idx] = {src, bits(n_src[src])} — single 8B random store
__global__ __launch_bounds__(256) void scatter_kernel(
    const int* __restrict__ src, const int* __restrict__ dst,
    const int* __restrict__ rowptr, int* __restrict__ cursor,
    const float* __restrict__ n_src,
    int2* __restrict__ csr_e) {
  int t = blockIdx.x * 256 + threadIdx.x;
  int r = blockIdx.y;
  if (t < NE) {
    int s = src[r * NE + t], v = dst[r * NE + t];
    int pos = atomicAdd(&cursor[r * NN + v], 1);
    int idx = r * NE + rowptr[(size_t)r * (NN + 1) + v] + pos;
    csr_e[idx] = make_int2(s, __float_as_int(n_src[r * NN + s]));
  }
}

// ---------------- weight / feature prep ----------------

// wt[layer][n][r*256+k] = W[layer][r][k][n]  (bf16, B^T layout for GEMM)
__global__ __launch_bounds__(256) void prep_w_kernel(
    const float* __restrict__ W1, const float* __restrict__ W2,
    unsigned short* __restrict__ wt1, unsigned short* __restrict__ wt2) {
  int t = blockIdx.x * 256 + threadIdx.x;   // 2*3*256*256
  int lay = t / (NR * NF * NF);
  int rem = t % (NR * NF * NF);
  int r = rem / (NF * NF);
  int k = (rem / NF) % NF;
  int n = rem % NF;
  const float* W = lay ? W2 : W1;
  unsigned short* wt = lay ? wt2 : wt1;
  wt[(size_t)n * NK + r * NF + k] = f2bfu(W[((size_t)r * NF + k) * NF + n]);
}

__global__ __launch_bounds__(256) void prep_bias_kernel(
    const float* __restrict__ b1, const float* __restrict__ b2,
    float* __restrict__ bs1, float* __restrict__ bs2) {
  int t = blockIdx.x * 256 + threadIdx.x;   // 512
  if (t < 2 * NF) {
    int lay = t / NF, n = t % NF;
    const float* b = lay ? b2 : b1;
    float* bs = lay ? bs2 : bs1;
    bs[n] = b[n] + b[NF + n] + b[2 * NF + n];
  }
}

__global__ __launch_bounds__(256) void cast_kernel(
    const float* __restrict__ in, unsigned short* __restrict__ out, int n4) {
  int t = blockIdx.x * 256 + threadIdx.x;
  if (t < n4) {
    floatx4 v = *(const floatx4*)&in[(size_t)t * 4];
    ushortx4 o;
    o.x = f2bfu(v.x); o.y = f2bfu(v.y); o.z = f2bfu(v.z); o.w = f2bfu(v.w);
    *(ushortx4*)&out[(size_t)t * 4] = o;
  }
}

// ---------------- SpMM: one wave per (node, relation), pull via CSR ----------------
// Half-wave edge pairs: lanes 0-31 edge e, lanes 32-63 edge e+1; each lane
// loads 16B (8 cols). Unroll-2 pairs -> 4 edges in flight. Cross-half combine
// via shfl_xor(32).

__global__ __launch_bounds__(256) void spmm_kernel(
    const unsigned short* __restrict__ x,   // [NN][256] bf16
    const int* __restrict__ rowptr, const int2* __restrict__ csr_e,
    const float* __restrict__ n_dst,
    unsigned short* __restrict__ agg) {     // [NN][768] bf16
  int wid = threadIdx.x >> 6, l = threadIdx.x & 63;
  int r = blockIdx.y;
  int v = blockIdx.x * 4 + wid;
  if (v >= NN) return;
  int e0 = rowptr[(size_t)r * (NN + 1) + v];
  int e1 = rowptr[(size_t)r * (NN + 1) + v + 1];
  const int2* ce = csr_e + (size_t)r * NE;
  const int half = l >> 5;        // 0: edge e, 1: edge e+1
  const int c8 = (l & 31) * 8;    // this lane's 8-col strip

  float a[8];
#pragma unroll
  for (int j = 0; j < 8; ++j) a[j] = 0.f;

  int e = e0;
  for (; e + 4 <= e1; e += 4) {   // two full pairs
    int2 p0 = ce[e + half];
    int2 p1 = ce[e + 2 + half];
    float w0 = __int_as_float(p0.y), w1 = __int_as_float(p1.y);
    ushortx8 x0 = *(const ushortx8*)&x[(size_t)p0.x * NF + c8];
    ushortx8 x1 = *(const ushortx8*)&x[(size_t)p1.x * NF + c8];
#pragma unroll
    for (int j = 0; j < 8; ++j) a[j] += w0 * bfu2f(x0[j]) + w1 * bfu2f(x1[j]);
  }
  for (; e < e1; e += 2) {        // remainder pair (possibly half-phantom)
    int idx = e + half;
    bool ok = idx < e1;
    int2 p = ok ? ce[idx] : make_int2(0, 0);
    float w = ok ? __int_as_float(p.y) : 0.f;
    ushortx8 xv = *(const ushortx8*)&x[(size_t)p.x * NF + c8];
#pragma unroll
    for (int j = 0; j < 8; ++j) a[j] += w * bfu2f(xv[j]);
  }

#pragma unroll
  for (int j = 0; j < 8; ++j) a[j] += __shfl_xor(a[j], 32);

  if (l < 32) {
    float nd = n_dst[r * NN + v];
    ushortx8 o;
#pragma unroll
    for (int j = 0; j < 8; ++j) o[j] = f2bfu(a[j] * nd);
    *(ushortx8*)&agg[(size_t)v * NK + r * NF + c8] = o;
  }
}

// ---------------- GEMM: [M,768] @ [768,256], BN=256 full width ----------------

__global__ __launch_bounds__(256, 2) void gemm_kernel(
    const unsigned short* __restrict__ A,    // [M][768] bf16
    const unsigned short* __restrict__ Bt,   // [256][768] bf16 (B^T: [col][K])
    const float* __restrict__ bias,          // [256]
    unsigned short* __restrict__ C,          // [M][256] bf16
    int M, int relu) {
  __shared__ unsigned short ldsA[128 * 32];   // [row][32]
  __shared__ unsigned short ldsB[256 * 32];   // [col][32]
  const int tid = threadIdx.x;
  const int l = tid & 63, wid = tid >> 6;
  const int row0 = blockIdx.x * 128;
  const int c0 = wid * 64;                    // wave's 64-col strip

  floatx4 acc[8][4];
#pragma unroll
  for (int i = 0; i < 8; ++i)
#pragma unroll
    for (int j = 0; j < 4; ++j)
#pragma unroll
      for (int q = 0; q < 4; ++q) acc[i][j][q] = 0.f;

  const int fr = l & 15, fk = (l >> 4) * 8;

  for (int kt = 0; kt < NK / 32; ++kt) {
    const int k0 = kt * 32;
    {
      int u = wid * 64 + l;                   // pass 0: units 0..255
      int arow = row0 + (u >> 2);
      if (arow >= M) arow = M - 1;
      gload16(A + (size_t)arow * NK + k0 + (u & 3) * 8, &ldsA[u * 8]);
      u += 256;                               // pass 1: units 256..511
      arow = row0 + (u >> 2);
      if (arow >= M) arow = M - 1;
      gload16(A + (size_t)arow * NK + k0 + (u & 3) * 8, &ldsA[u * 8]);
    }
#pragma unroll
    for (int p = 0; p < 4; ++p) {
      int u = p * 256 + wid * 64 + l;
      int col = u >> 2;
      gload16(Bt + (size_t)col * NK + k0 + (u & 3) * 8, &ldsB[u * 8]);
    }
    asm volatile("s_waitcnt vmcnt(0)" ::: "memory");
    __syncthreads();

    short8 af[8], bf[4];
#pragma unroll
    for (int m = 0; m < 8; ++m)
      af[m] = *(const short8*)&ldsA[(m * 16 + fr) * 32 + fk];
#pragma unroll
    for (int n = 0; n < 4; ++n)
      bf[n] = *(const short8*)&ldsB[(c0 + n * 16 + fr) * 32 + fk];
#pragma unroll
    for (int m = 0; m < 8; ++m)
#pragma unroll
      for (int n = 0; n < 4; ++n)
        acc[m][n] = __builtin_amdgcn_mfma_f32_16x16x32_bf16(af[m], bf[n], acc[m][n], 0, 0, 0);
    __syncthreads();
  }

  const int fq = l >> 4;
#pragma unroll
  for (int m = 0; m < 8; ++m) {
#pragma unroll
    for (int n = 0; n < 4; ++n) {
      int col = c0 + n * 16 + fr;
      float bv = bias[col];
#pragma unroll
      for (int q = 0; q < 4; ++q) {
        int row = row0 + m * 16 + fq * 4 + q;
        if (row < M) {
          float vv = acc[m][n][q] + bv;
          if (relu) vv = fmaxf(vv, 0.f);
          C[(size_t)row * NF + col] = f2bfu(vv);
        }
      }
    }
  }
}

// ---------------- pooling ----------------

__global__ __launch_bounds__(256) void pool_kernel(
    const unsigned short* __restrict__ h2, const int* __restrict__ gid,
    float* __restrict__ poolsum) {
  int c = threadIdx.x;                 // column 0..255
  int v0 = blockIdx.x * 256;
  int vend = min(v0 + 256, NN);
  float acc = 0.f;
  int curg = -1;
  for (int v = v0; v < vend; ++v) {
    int g = gid[v];                    // sorted -> few runs per chunk
    if (g != curg) {
      if (curg >= 0) atomicAdd(&poolsum[curg * NF + c], acc);
      curg = g; acc = 0.f;
    }
    acc += bfu2f(h2[(size_t)v * NF + c]);
  }
  if (curg >= 0) atomicAdd(&poolsum[curg * NF + c], acc);
}

__global__ __launch_bounds__(256) void final_kernel(
    const float* __restrict__ poolsum, const int* __restrict__ gcount,
    float* __restrict__ out) {
  int g = blockIdx.x, c = threadIdx.x;
  out[g * NF + c] = poolsum[g * NF + c] / fmaxf((float)gcount[g], 1.f);
}

// ---------------- launch ----------------

extern "C" void kernel_launch(void* const* d_in, const int* in_sizes, int n_in,
                              void* d_out, int out_size, void* d_ws, size_t ws_size,
                              hipStream_t stream) {
  const float* feat = (const float*)d_in[0];
  const int* src = (const int*)d_in[1];
  const int* dst = (const int*)d_in[2];
  const int* gid = (const int*)d_in[3];
  const float* W1 = (const float*)d_in[4];
  const float* b1 = (const float*)d_in[5];
  const float* W2 = (const float*)d_in[6];
  const float* b2 = (const float*)d_in[7];
  float* out = (float*)d_out;

  char* ws = (char*)d_ws;
  size_t off = 0;
  auto alloc = [&](size_t bytes) -> void* {
    void* p = ws + off;
    off = (off + bytes + 255) & ~(size_t)255;
    return p;
  };

  // zero-initialized block (single memset)
  int* deg_out = (int*)alloc((size_t)NR * NN * 4);
  int* deg_in  = (int*)alloc((size_t)NR * NN * 4);
  int* cursor  = (int*)alloc((size_t)NR * NN * 4);
  float* poolsum = (float*)alloc((size_t)NG * NF * 4);
  size_t zero_bytes = off;

  int* gcount  = (int*)alloc((size_t)NG * 4);
  int* blocksum = (int*)alloc((size_t)NR * SCAN_NB * 4);
  float* n_src = (float*)alloc((size_t)NR * NN * 4);
  float* n_dst = (float*)alloc((size_t)NR * NN * 4);
  int* rowptr  = (int*)alloc((size_t)NR * (NN + 1) * 4);
  int2* csr_e  = (int2*)alloc((size_t)NR * NE * 8);
  unsigned short* wt1 = (unsigned short*)alloc((size_t)NF * NK * 2);
  unsigned short* wt2 = (unsigned short*)alloc((size_t)NF * NK * 2);
  float* bs1 = (float*)alloc(NF * 4);
  float* bs2 = (float*)alloc(NF * 4);
  unsigned short* featbf = (unsigned short*)alloc((size_t)NN * NF * 2);
  unsigned short* h1 = (unsigned short*)alloc((size_t)NN * NF * 2);
  unsigned short* h2 = (unsigned short*)alloc((size_t)NN * NF * 2);
  unsigned short* agg = (unsigned short*)alloc((size_t)NN * NK * 2);
  (void)ws_size; (void)in_sizes; (void)n_in; (void)out_size;

  hipMemsetAsync(d_ws, 0, zero_bytes, stream);

  dim3 eg((NE + 255) / 256, NR);
  degree_kernel<<<eg, 256, 0, stream>>>(src, dst, deg_out, deg_in);
  gcount_kernel<<<1, 128, 0, stream>>>(gid, gcount);
  norm_kernel<<<(NR * NN + 255) / 256, 256, 0, stream>>>(deg_out, deg_in, n_src, n_dst);
  scan_phaseA<<<dim3(SCAN_NB, NR), 256, 0, stream>>>(deg_in, blocksum);
  scan_phaseB<<<NR, 128, 0, stream>>>(blocksum, rowptr);
  scan_phaseC<<<dim3(SCAN_NB, NR), 256, 0, stream>>>(deg_in, blocksum, rowptr);
  scatter_kernel<<<eg, 256, 0, stream>>>(src, dst, rowptr, cursor, n_src, csr_e);

  prep_w_kernel<<<(2 * NR * NF * NF) / 256, 256, 0, stream>>>(W1, W2, wt1, wt2);
  prep_bias_kernel<<<2, 256, 0, stream>>>(b1, b2, bs1, bs2);
  cast_kernel<<<(NN * NF / 4 + 255) / 256, 256, 0, stream>>>(feat, featbf, NN * NF / 4);

  dim3 sg((NN + 3) / 4, NR);
  // layer 1
  spmm_kernel<<<sg, 256, 0, stream>>>(featbf, rowptr, csr_e, n_dst, agg);
  gemm_kernel<<<(NN + 127) / 128, 256, 0, stream>>>(agg, wt1, bs1, h1, NN, 1);
  // layer 2
  spmm_kernel<<<sg, 256, 0, stream>>>(h1, rowptr, csr_e, n_dst, agg);
  gemm_kernel<<<(NN + 127) / 128, 256, 0, stream>>>(agg, wt2, bs2, h2, NN, 0);
  // pooling
  pool_kernel<<<(NN + 255) / 256, 256, 0, stream>>>(h2, gid, poolsum);
  final_kernel<<<NG, 256, 0, stream>>>(poolsum, gcount, out);
}

// Round 6
// 713.248 us; speedup vs baseline: 1.7912x; 1.0072x over previous
//
#include <hip/hip_runtime.h>
#include <stdint.h>

#define NN 100000   // nodes
#define NE 400000   // edges per relation
#define NR 3        // relations
#define NF 256      // feature dim
#define NK 768      // NR*NF concatenated K
#define NG 128      // graphs
#define SCAN_NB ((NN + 1023) / 1024)   // 98 chunks of 1024

typedef __attribute__((ext_vector_type(4))) unsigned short ushortx4;
typedef __attribute__((ext_vector_type(8))) unsigned short ushortx8;
typedef __attribute__((ext_vector_type(8))) short short8;
typedef __attribute__((ext_vector_type(4))) float floatx4;

static __device__ __forceinline__ unsigned short f2bfu(float f) {
  union { float f; uint32_t u; } c; c.f = f;
  uint32_t x = c.u;
  uint32_t r = (x + 0x7fffu + ((x >> 16) & 1u)) >> 16;
  return (unsigned short)r;
}
static __device__ __forceinline__ float bfu2f(unsigned short u) {
  union { uint32_t u; float f; } c; c.u = ((uint32_t)u) << 16;
  return c.f;
}

static __device__ __forceinline__ void gload16(const void* g, void* l) {
  __builtin_amdgcn_global_load_lds(
      (const __attribute__((address_space(1))) uint32_t*)g,
      (__attribute__((address_space(3))) uint32_t*)l, 16, 0, 0);
}

// ---------------- graph preprocessing ----------------

__global__ __launch_bounds__(256) void degree_kernel(
    const int* __restrict__ src, const int* __restrict__ dst,
    int* __restrict__ deg_out, int* __restrict__ deg_in) {
  int t = blockIdx.x * 256 + threadIdx.x;
  int r = blockIdx.y;
  if (t < NE) {
    atomicAdd(&deg_out[r * NN + src[r * NE + t]], 1);
    atomicAdd(&deg_in[r * NN + dst[r * NE + t]], 1);
  }
}

// gid is sorted: count[g] = lb(g+1) - lb(g) via binary search. No atomics.
__global__ __launch_bounds__(128) void gcount_kernel(
    const int* __restrict__ gid, int* __restrict__ gcount) {
  int g = threadIdx.x;  // 0..127
  int lo = 0, hi = NN;
  while (lo < hi) { int mid = (lo + hi) >> 1; if (gid[mid] < g) lo = mid + 1; else hi = mid; }
  int a = lo;
  lo = 0; hi = NN;
  while (lo < hi) { int mid = (lo + hi) >> 1; if (gid[mid] < g + 1) lo = mid + 1; else hi = mid; }
  gcount[g] = lo - a;
}

__global__ __launch_bounds__(256) void norm_kernel(
    const int* __restrict__ deg_out, const int* __restrict__ deg_in,
    float* __restrict__ n_src, float* __restrict__ n_dst) {
  int t = blockIdx.x * 256 + threadIdx.x;
  if (t < NR * NN) {
    int dof = deg_out[t], din = deg_in[t];
    n_src[t] = dof > 0 ? rsqrtf((float)dof) : 0.f;
    n_dst[t] = din > 0 ? rsqrtf((float)din) : 0.f;
  }
}

// ---- multi-block exclusive scan of deg_in -> rowptr (3 phases) ----

__global__ __launch_bounds__(256) void scan_phaseA(
    const int* __restrict__ deg_in, int* __restrict__ blocksum) {
  int r = blockIdx.y, b = blockIdx.x, tid = threadIdx.x;
  const int* deg = deg_in + (size_t)r * NN;
  int base = b * 1024 + tid * 4;
  int s = 0;
#pragma unroll
  for (int i = 0; i < 4; ++i) { int idx = base + i; if (idx < NN) s += deg[idx]; }
  __shared__ int red[256];
  red[tid] = s; __syncthreads();
  for (int off = 128; off > 0; off >>= 1) {
    if (tid < off) red[tid] += red[tid + off];
    __syncthreads();
  }
  if (tid == 0) blocksum[r * SCAN_NB + b] = red[0];
}

__global__ __launch_bounds__(128) void scan_phaseB(
    int* __restrict__ blocksum, int* __restrict__ rowptr) {
  int r = blockIdx.x, tid = threadIdx.x;
  int* bs = blocksum + r * SCAN_NB;
  __shared__ int buf[128];
  int v = (tid < SCAN_NB) ? bs[tid] : 0;
  buf[tid] = v; __syncthreads();
  for (int off = 1; off < 128; off <<= 1) {
    int t = (tid >= off) ? buf[tid - off] : 0;
    __syncthreads();
    buf[tid] += t;
    __syncthreads();
  }
  if (tid < SCAN_NB) bs[tid] = buf[tid] - v;   // exclusive chunk offset
  if (tid == 127) rowptr[(size_t)r * (NN + 1) + NN] = buf[127];
}

__global__ __launch_bounds__(256) void scan_phaseC(
    const int* __restrict__ deg_in, const int* __restrict__ blocksum,
    int* __restrict__ rowptr) {
  int r = blockIdx.y, b = blockIdx.x, tid = threadIdx.x;
  const int* deg = deg_in + (size_t)r * NN;
  int* rp = rowptr + (size_t)r * (NN + 1);
  int base = b * 1024 + tid * 4;
  int v[4]; int s = 0;
#pragma unroll
  for (int i = 0; i < 4; ++i) { int idx = base + i; v[i] = (idx < NN) ? deg[idx] : 0; s += v[i]; }
  __shared__ int buf[256];
  buf[tid] = s; __syncthreads();
  for (int off = 1; off < 256; off <<= 1) {
    int t = (tid >= off) ? buf[tid - off] : 0;
    __syncthreads();
    buf[tid] += t;
    __syncthreads();
  }
  int excl = buf[tid] - s + blocksum[r * SCAN_NB + b];
#pragma unroll
  for (int i = 0; i < 4; ++i) {
    int idx = base + i;
    if (idx < NN) rp[idx] = excl;
    excl += v[i];
  }
}

// cursor is a COPY of rowptr (layout [r][NN+1]); atomicAdd gives the absolute
// CSR slot directly -> no random rowptr load per edge.
__global__ __launch_bounds__(256) void scatter_kernel(
    const int* __restrict__ src, const int* __restrict__ dst,
    int* __restrict__ cursor, const float* __restrict__ n_src,
    int2* __restrict__ csr_e) {
  int t = blockIdx.x * 256 + threadIdx.x;
  int r = blockIdx.y;
  if (t < NE) {
    int s = src[r * NE + t], v = dst[r * NE + t];
    int pos = atomicAdd(&cursor[r * (NN + 1) + v], 1);   // absolute within relation
    csr_e[(size_t)r * NE + pos] = make_int2(s, __float_as_int(n_src[r * NN + s]));
  }
}

// ---------------- weight / feature prep ----------------

// wt[layer][n][r*256+k] = W[layer][r][k][n]  (bf16, B^T layout for GEMM)
__global__ __launch_bounds__(256) void prep_w_kernel(
    const float* __restrict__ W1, const float* __restrict__ W2,
    unsigned short* __restrict__ wt1, unsigned short* __restrict__ wt2) {
  int t = blockIdx.x * 256 + threadIdx.x;   // 2*3*256*256
  int lay = t / (NR * NF * NF);
  int rem = t % (NR * NF * NF);
  int r = rem / (NF * NF);
  int k = (rem / NF) % NF;
  int n = rem % NF;
  const float* W = lay ? W2 : W1;
  unsigned short* wt = lay ? wt2 : wt1;
  wt[(size_t)n * NK + r * NF + k] = f2bfu(W[((size_t)r * NF + k) * NF + n]);
}

__global__ __launch_bounds__(256) void prep_bias_kernel(
    const float* __restrict__ b1, const float* __restrict__ b2,
    float* __restrict__ bs1, float* __restrict__ bs2) {
  int t = blockIdx.x * 256 + threadIdx.x;   // 512
  if (t < 2 * NF) {
    int lay = t / NF, n = t % NF;
    const float* b = lay ? b2 : b1;
    float* bs = lay ? bs2 : bs1;
    bs[n] = b[n] + b[NF + n] + b[2 * NF + n];
  }
}

__global__ __launch_bounds__(256) void cast_kernel(
    const float* __restrict__ in, unsigned short* __restrict__ out, int n4) {
  int t = blockIdx.x * 256 + threadIdx.x;
  if (t < n4) {
    floatx4 v = *(const floatx4*)&in[(size_t)t * 4];
    ushortx4 o;
    o.x = f2bfu(v.x); o.y = f2bfu(v.y); o.z = f2bfu(v.z); o.w = f2bfu(v.w);
    *(ushortx4*)&out[(size_t)t * 4] = o;
  }
}

// ---------------- SpMM: one wave per NODE, all 3 relations interleaved ----------------
// Per while-iteration: one edge-pair per relation -> 3 independent gather chains
// in flight even for degree-1 rows. Half-wave (32 lanes x 16B) covers a 512B row.
// All loop conditions are wave-uniform (rowptr-derived) -> cheap s_cbranch.

__global__ __launch_bounds__(256) void spmm_kernel(
    const unsigned short* __restrict__ x,   // [NN][256] bf16
    const int* __restrict__ rowptr, const int2* __restrict__ csr_e,
    const float* __restrict__ n_dst,
    unsigned short* __restrict__ agg) {     // [NN][768] bf16
  int wid = threadIdx.x >> 6, l = threadIdx.x & 63;
  int v = blockIdx.x * 4 + wid;
  if (v >= NN) return;
  const int half = l >> 5;        // 0: edge e, 1: edge e+1
  const int c8 = (l & 31) * 8;    // this lane's 8-col strip

  int ea = rowptr[v],                e1a = rowptr[v + 1];
  int eb = rowptr[(NN + 1) + v],     e1b = rowptr[(NN + 1) + v + 1];
  int ec = rowptr[2 * (NN + 1) + v], e1c = rowptr[2 * (NN + 1) + v + 1];
  const int2* cea = csr_e;
  const int2* ceb = csr_e + (size_t)NE;
  const int2* cec = csr_e + (size_t)2 * NE;

  float a[NR][8];
#pragma unroll
  for (int r = 0; r < NR; ++r)
#pragma unroll
    for (int j = 0; j < 8; ++j) a[r][j] = 0.f;

  while (ea < e1a || eb < e1b || ec < e1c) {
    if (ea < e1a) {
      if (ea + half < e1a) {
        int2 p = cea[ea + half];
        float w = __int_as_float(p.y);
        ushortx8 xv = *(const ushortx8*)&x[(size_t)p.x * NF + c8];
#pragma unroll
        for (int j = 0; j < 8; ++j) a[0][j] += w * bfu2f(xv[j]);
      }
      ea += 2;
    }
    if (eb < e1b) {
      if (eb + half < e1b) {
        int2 p = ceb[eb + half];
        float w = __int_as_float(p.y);
        ushortx8 xv = *(const ushortx8*)&x[(size_t)p.x * NF + c8];
#pragma unroll
        for (int j = 0; j < 8; ++j) a[1][j] += w * bfu2f(xv[j]);
      }
      eb += 2;
    }
    if (ec < e1c) {
      if (ec + half < e1c) {
        int2 p = cec[ec + half];
        float w = __int_as_float(p.y);
        ushortx8 xv = *(const ushortx8*)&x[(size_t)p.x * NF + c8];
#pragma unroll
        for (int j = 0; j < 8; ++j) a[2][j] += w * bfu2f(xv[j]);
      }
      ec += 2;
    }
  }

#pragma unroll
  for (int r = 0; r < NR; ++r)
#pragma unroll
    for (int j = 0; j < 8; ++j) a[r][j] += __shfl_xor(a[r][j], 32);

  if (l < 32) {
#pragma unroll
    for (int r = 0; r < NR; ++r) {
      float nd = n_dst[r * NN + v];
      ushortx8 o;
#pragma unroll
      for (int j = 0; j < 8; ++j) o[j] = f2bfu(a[r][j] * nd);
      *(ushortx8*)&agg[(size_t)v * NK + r * NF + c8] = o;
    }
  }
}

// ---------------- GEMM: [M,768] @ [768,256], BN=256 full width ----------------

__global__ __launch_bounds__(256, 2) void gemm_kernel(
    const unsigned short* __restrict__ A,    // [M][768] bf16
    const unsigned short* __restrict__ Bt,   // [256][768] bf16 (B^T: [col][K])
    const float* __restrict__ bias,          // [256]
    unsigned short* __restrict__ C,          // [M][256] bf16
    int M, int relu) {
  __shared__ unsigned short ldsA[128 * 32];   // [row][32]
  __shared__ unsigned short ldsB[256 * 32];   // [col][32]
  const int tid = threadIdx.x;
  const int l = tid & 63, wid = tid >> 6;
  const int row0 = blockIdx.x * 128;
  const int c0 = wid * 64;                    // wave's 64-col strip

  floatx4 acc[8][4];
#pragma unroll
  for (int i = 0; i < 8; ++i)
#pragma unroll
    for (int j = 0; j < 4; ++j)
#pragma unroll
      for (int q = 0; q < 4; ++q) acc[i][j][q] = 0.f;

  const int fr = l & 15, fk = (l >> 4) * 8;

  for (int kt = 0; kt < NK / 32; ++kt) {
    const int k0 = kt * 32;
    {
      int u = wid * 64 + l;                   // pass 0: units 0..255
      int arow = row0 + (u >> 2);
      if (arow >= M) arow = M - 1;
      gload16(A + (size_t)arow * NK + k0 + (u & 3) * 8, &ldsA[u * 8]);
      u += 256;                               // pass 1: units 256..511
      arow = row0 + (u >> 2);
      if (arow >= M) arow = M - 1;
      gload16(A + (size_t)arow * NK + k0 + (u & 3) * 8, &ldsA[u * 8]);
    }
#pragma unroll
    for (int p = 0; p < 4; ++p) {
      int u = p * 256 + wid * 64 + l;
      int col = u >> 2;
      gload16(Bt + (size_t)col * NK + k0 + (u & 3) * 8, &ldsB[u * 8]);
    }
    asm volatile("s_waitcnt vmcnt(0)" ::: "memory");
    __syncthreads();

    short8 af[8], bf[4];
#pragma unroll
    for (int m = 0; m < 8; ++m)
      af[m] = *(const short8*)&ldsA[(m * 16 + fr) * 32 + fk];
#pragma unroll
    for (int n = 0; n < 4; ++n)
      bf[n] = *(const short8*)&ldsB[(c0 + n * 16 + fr) * 32 + fk];
#pragma unroll
    for (int m = 0; m < 8; ++m)
#pragma unroll
      for (int n = 0; n < 4; ++n)
        acc[m][n] = __builtin_amdgcn_mfma_f32_16x16x32_bf16(af[m], bf[n], acc[m][n], 0, 0, 0);
    __syncthreads();
  }

  const int fq = l >> 4;
#pragma unroll
  for (int m = 0; m < 8; ++m) {
#pragma unroll
    for (int n = 0; n < 4; ++n) {
      int col = c0 + n * 16 + fr;
      float bv = bias[col];
#pragma unroll
      for (int q = 0; q < 4; ++q) {
        int row = row0 + m * 16 + fq * 4 + q;
        if (row < M) {
          float vv = acc[m][n][q] + bv;
          if (relu) vv = fmaxf(vv, 0.f);
          C[(size_t)row * NF + col] = f2bfu(vv);
        }
      }
    }
  }
}

// ---------------- pooling ----------------

__global__ __launch_bounds__(256) void pool_kernel(
    const unsigned short* __restrict__ h2, const int* __restrict__ gid,
    float* __restrict__ poolsum) {
  int c = threadIdx.x;                 // column 0..255
  int v0 = blockIdx.x * 256;
  int vend = min(v0 + 256, NN);
  float acc = 0.f;
  int curg = -1;
  for (int v = v0; v < vend; ++v) {
    int g = gid[v];                    // sorted -> few runs per chunk
    if (g != curg) {
      if (curg >= 0) atomicAdd(&poolsum[curg * NF + c], acc);
      curg = g; acc = 0.f;
    }
    acc += bfu2f(h2[(size_t)v * NF + c]);
  }
  if (curg >= 0) atomicAdd(&poolsum[curg * NF + c], acc);
}

__global__ __launch_bounds__(256) void final_kernel(
    const float* __restrict__ poolsum, const int* __restrict__ gcount,
    float* __restrict__ out) {
  int g = blockIdx.x, c = threadIdx.x;
  out[g * NF + c] = poolsum[g * NF + c] / fmaxf((float)gcount[g], 1.f);
}

// ---------------- launch ----------------

extern "C" void kernel_launch(void* const* d_in, const int* in_sizes, int n_in,
                              void* d_out, int out_size, void* d_ws, size_t ws_size,
                              hipStream_t stream) {
  const float* feat = (const float*)d_in[0];
  const int* src = (const int*)d_in[1];
  const int* dst = (const int*)d_in[2];
  const int* gid = (const int*)d_in[3];
  const float* W1 = (const float*)d_in[4];
  const float* b1 = (const float*)d_in[5];
  const float* W2 = (const float*)d_in[6];
  const float* b2 = (const float*)d_in[7];
  float* out = (float*)d_out;

  char* ws = (char*)d_ws;
  size_t off = 0;
  auto alloc = [&](size_t bytes) -> void* {
    void* p = ws + off;
    off = (off + bytes + 255) & ~(size_t)255;
    return p;
  };

  // zero-initialized block (single memset)
  int* deg_out = (int*)alloc((size_t)NR * NN * 4);
  int* deg_in  = (int*)alloc((size_t)NR * NN * 4);
  float* poolsum = (float*)alloc((size_t)NG * NF * 4);
  size_t zero_bytes = off;

  int* cursor  = (int*)alloc((size_t)NR * (NN + 1) * 4);
  int* gcount  = (int*)alloc((size_t)NG * 4);
  int* blocksum = (int*)alloc((size_t)NR * SCAN_NB * 4);
  float* n_src = (float*)alloc((size_t)NR * NN * 4);
  float* n_dst = (float*)alloc((size_t)NR * NN * 4);
  int* rowptr  = (int*)alloc((size_t)NR * (NN + 1) * 4);
  int2* csr_e  = (int2*)alloc((size_t)NR * NE * 8);
  unsigned short* wt1 = (unsigned short*)alloc((size_t)NF * NK * 2);
  unsigned short* wt2 = (unsigned short*)alloc((size_t)NF * NK * 2);
  float* bs1 = (float*)alloc(NF * 4);
  float* bs2 = (float*)alloc(NF * 4);
  unsigned short* featbf = (unsigned short*)alloc((size_t)NN * NF * 2);
  unsigned short* h1 = (unsigned short*)alloc((size_t)NN * NF * 2);
  unsigned short* h2 = (unsigned short*)alloc((size_t)NN * NF * 2);
  unsigned short* agg = (unsigned short*)alloc((size_t)NN * NK * 2);
  (void)ws_size; (void)in_sizes; (void)n_in; (void)out_size;

  hipMemsetAsync(d_ws, 0, zero_bytes, stream);

  dim3 eg((NE + 255) / 256, NR);
  degree_kernel<<<eg, 256, 0, stream>>>(src, dst, deg_out, deg_in);
  gcount_kernel<<<1, 128, 0, stream>>>(gid, gcount);
  norm_kernel<<<(NR * NN + 255) / 256, 256, 0, stream>>>(deg_out, deg_in, n_src, n_dst);
  scan_phaseA<<<dim3(SCAN_NB, NR), 256, 0, stream>>>(deg_in, blocksum);
  scan_phaseB<<<NR, 128, 0, stream>>>(blocksum, rowptr);
  scan_phaseC<<<dim3(SCAN_NB, NR), 256, 0, stream>>>(deg_in, blocksum, rowptr);
  hipMemcpyAsync(cursor, rowptr, (size_t)NR * (NN + 1) * 4,
                 hipMemcpyDeviceToDevice, stream);
  scatter_kernel<<<eg, 256, 0, stream>>>(src, dst, cursor, n_src, csr_e);

  prep_w_kernel<<<(2 * NR * NF * NF) / 256, 256, 0, stream>>>(W1, W2, wt1, wt2);
  prep_bias_kernel<<<2, 256, 0, stream>>>(b1, b2, bs1, bs2);
  cast_kernel<<<(NN * NF / 4 + 255) / 256, 256, 0, stream>>>(feat, featbf, NN * NF / 4);

  // layer 1
  spmm_kernel<<<(NN + 3) / 4, 256, 0, stream>>>(featbf, rowptr, csr_e, n_dst, agg);
  gemm_kernel<<<(NN + 127) / 128, 256, 0, stream>>>(agg, wt1, bs1, h1, NN, 1);
  // layer 2
  spmm_kernel<<<(NN + 3) / 4, 256, 0, stream>>>(h1, rowptr, csr_e, n_dst, agg);
  gemm_kernel<<<(NN + 127) / 128, 256, 0, stream>>>(agg, wt2, bs2, h2, NN, 0);
  // pooling
  pool_kernel<<<(NN + 255) / 256, 256, 0, stream>>>(h2, gid, poolsum);
  final_kernel<<<NG, 256, 0, stream>>>(poolsum, gcount, out);
}

// Round 7
// 710.992 us; speedup vs baseline: 1.7969x; 1.0032x over previous
//
#include <hip/hip_runtime.h>
#include <stdint.h>

#define NN 100000   // nodes
#define NE 400000   // edges per relation
#define NR 3        // relations
#define NF 256      // feature dim
#define NK 768      // NR*NF concatenated K
#define NG 128      // graphs
#define SCAN_NB ((NN + 1023) / 1024)   // 98 chunks of 1024

typedef __attribute__((ext_vector_type(4))) unsigned short ushortx4;
typedef __attribute__((ext_vector_type(8))) unsigned short ushortx8;
typedef __attribute__((ext_vector_type(8))) short short8;
typedef __attribute__((ext_vector_type(4))) float floatx4;

static __device__ __forceinline__ unsigned short f2bfu(float f) {
  union { float f; uint32_t u; } c; c.f = f;
  uint32_t x = c.u;
  uint32_t r = (x + 0x7fffu + ((x >> 16) & 1u)) >> 16;
  return (unsigned short)r;
}
static __device__ __forceinline__ float bfu2f(unsigned short u) {
  union { uint32_t u; float f; } c; c.u = ((uint32_t)u) << 16;
  return c.f;
}

static __device__ __forceinline__ void gload16(const void* g, void* l) {
  __builtin_amdgcn_global_load_lds(
      (const __attribute__((address_space(1))) uint32_t*)g,
      (__attribute__((address_space(3))) uint32_t*)l, 16, 0, 0);
}

// ---------------- graph preprocessing ----------------

__global__ __launch_bounds__(256) void degree_kernel(
    const int* __restrict__ src, const int* __restrict__ dst,
    int* __restrict__ deg_out, int* __restrict__ deg_in) {
  int t = blockIdx.x * 256 + threadIdx.x;
  int r = blockIdx.y;
  if (t < NE) {
    atomicAdd(&deg_out[r * NN + src[r * NE + t]], 1);
    atomicAdd(&deg_in[r * NN + dst[r * NE + t]], 1);
  }
}

// gid is sorted: count[g] = lb(g+1) - lb(g) via binary search. No atomics.
__global__ __launch_bounds__(128) void gcount_kernel(
    const int* __restrict__ gid, int* __restrict__ gcount) {
  int g = threadIdx.x;  // 0..127
  int lo = 0, hi = NN;
  while (lo < hi) { int mid = (lo + hi) >> 1; if (gid[mid] < g) lo = mid + 1; else hi = mid; }
  int a = lo;
  lo = 0; hi = NN;
  while (lo < hi) { int mid = (lo + hi) >> 1; if (gid[mid] < g + 1) lo = mid + 1; else hi = mid; }
  gcount[g] = lo - a;
}

__global__ __launch_bounds__(256) void norm_kernel(
    const int* __restrict__ deg_out, const int* __restrict__ deg_in,
    float* __restrict__ n_src, float* __restrict__ n_dst) {
  int t = blockIdx.x * 256 + threadIdx.x;
  if (t < NR * NN) {
    int dof = deg_out[t], din = deg_in[t];
    n_src[t] = dof > 0 ? rsqrtf((float)dof) : 0.f;
    n_dst[t] = din > 0 ? rsqrtf((float)din) : 0.f;
  }
}

// ---- multi-block exclusive scan of deg_in -> rowptr (3 phases) ----

__global__ __launch_bounds__(256) void scan_phaseA(
    const int* __restrict__ deg_in, int* __restrict__ blocksum) {
  int r = blockIdx.y, b = blockIdx.x, tid = threadIdx.x;
  const int* deg = deg_in + (size_t)r * NN;
  int base = b * 1024 + tid * 4;
  int s = 0;
#pragma unroll
  for (int i = 0; i < 4; ++i) { int idx = base + i; if (idx < NN) s += deg[idx]; }
  __shared__ int red[256];
  red[tid] = s; __syncthreads();
  for (int off = 128; off > 0; off >>= 1) {
    if (tid < off) red[tid] += red[tid + off];
    __syncthreads();
  }
  if (tid == 0) blocksum[r * SCAN_NB + b] = red[0];
}

__global__ __launch_bounds__(128) void scan_phaseB(
    int* __restrict__ blocksum, int* __restrict__ rowptr) {
  int r = blockIdx.x, tid = threadIdx.x;
  int* bs = blocksum + r * SCAN_NB;
  __shared__ int buf[128];
  int v = (tid < SCAN_NB) ? bs[tid] : 0;
  buf[tid] = v; __syncthreads();
  for (int off = 1; off < 128; off <<= 1) {
    int t = (tid >= off) ? buf[tid - off] : 0;
    __syncthreads();
    buf[tid] += t;
    __syncthreads();
  }
  if (tid < SCAN_NB) bs[tid] = buf[tid] - v;   // exclusive chunk offset
  if (tid == 127) rowptr[(size_t)r * (NN + 1) + NN] = buf[127];
}

__global__ __launch_bounds__(256) void scan_phaseC(
    const int* __restrict__ deg_in, const int* __restrict__ blocksum,
    int* __restrict__ rowptr) {
  int r = blockIdx.y, b = blockIdx.x, tid = threadIdx.x;
  const int* deg = deg_in + (size_t)r * NN;
  int* rp = rowptr + (size_t)r * (NN + 1);
  int base = b * 1024 + tid * 4;
  int v[4]; int s = 0;
#pragma unroll
  for (int i = 0; i < 4; ++i) { int idx = base + i; v[i] = (idx < NN) ? deg[idx] : 0; s += v[i]; }
  __shared__ int buf[256];
  buf[tid] = s; __syncthreads();
  for (int off = 1; off < 256; off <<= 1) {
    int t = (tid >= off) ? buf[tid - off] : 0;
    __syncthreads();
    buf[tid] += t;
    __syncthreads();
  }
  int excl = buf[tid] - s + blocksum[r * SCAN_NB + b];
#pragma unroll
  for (int i = 0; i < 4; ++i) {
    int idx = base + i;
    if (idx < NN) rp[idx] = excl;
    excl += v[i];
  }
}

// cursor is a COPY of rowptr (layout [r][NN+1]); atomicAdd gives the absolute
// CSR slot directly -> no random rowptr load per edge.
__global__ __launch_bounds__(256) void scatter_kernel(
    const int* __restrict__ src, const int* __restrict__ dst,
    int* __restrict__ cursor, const float* __restrict__ n_src,
    int2* __restrict__ csr_e) {
  int t = blockIdx.x * 256 + threadIdx.x;
  int r = blockIdx.y;
  if (t < NE) {
    int s = src[r * NE + t], v = dst[r * NE + t];
    int pos = atomicAdd(&cursor[r * (NN + 1) + v], 1);   // absolute within relation
    csr_e[(size_t)r * NE + pos] = make_int2(s, __float_as_int(n_src[r * NN + s]));
  }
}

// ---------------- weight / feature prep ----------------

// wt[layer][n][r*256+k] = W[layer][r][k][n]  (bf16, B^T layout for GEMM)
__global__ __launch_bounds__(256) void prep_w_kernel(
    const float* __restrict__ W1, const float* __restrict__ W2,
    unsigned short* __restrict__ wt1, unsigned short* __restrict__ wt2) {
  int t = blockIdx.x * 256 + threadIdx.x;   // 2*3*256*256
  int lay = t / (NR * NF * NF);
  int rem = t % (NR * NF * NF);
  int r = rem / (NF * NF);
  int k = (rem / NF) % NF;
  int n = rem % NF;
  const float* W = lay ? W2 : W1;
  unsigned short* wt = lay ? wt2 : wt1;
  wt[(size_t)n * NK + r * NF + k] = f2bfu(W[((size_t)r * NF + k) * NF + n]);
}

__global__ __launch_bounds__(256) void prep_bias_kernel(
    const float* __restrict__ b1, const float* __restrict__ b2,
    float* __restrict__ bs1, float* __restrict__ bs2) {
  int t = blockIdx.x * 256 + threadIdx.x;   // 512
  if (t < 2 * NF) {
    int lay = t / NF, n = t % NF;
    const float* b = lay ? b2 : b1;
    float* bs = lay ? bs2 : bs1;
    bs[n] = b[n] + b[NF + n] + b[2 * NF + n];
  }
}

// NT load: feat is read exactly once -> don't let 100 MB of f32 pollute L3.
__global__ __launch_bounds__(256) void cast_kernel(
    const float* __restrict__ in, unsigned short* __restrict__ out, int n4) {
  int t = blockIdx.x * 256 + threadIdx.x;
  if (t < n4) {
    floatx4 v = __builtin_nontemporal_load((const floatx4*)&in[(size_t)t * 4]);
    ushortx4 o;
    o.x = f2bfu(v.x); o.y = f2bfu(v.y); o.z = f2bfu(v.z); o.w = f2bfu(v.w);
    *(ushortx4*)&out[(size_t)t * 4] = o;
  }
}

// ---------------- SpMM: one wave per NODE, all 3 relations interleaved ----------------
// agg store is NON-TEMPORAL: write-once-read-once stream must not evict the
// gather source x from L3 (R6 counters: FETCH 301MB vs 51MB source = thrash).

__global__ __launch_bounds__(256) void spmm_kernel(
    const unsigned short* __restrict__ x,   // [NN][256] bf16
    const int* __restrict__ rowptr, const int2* __restrict__ csr_e,
    const float* __restrict__ n_dst,
    unsigned short* __restrict__ agg) {     // [NN][768] bf16
  int wid = threadIdx.x >> 6, l = threadIdx.x & 63;
  int v = blockIdx.x * 4 + wid;
  if (v >= NN) return;
  const int half = l >> 5;        // 0: edge e, 1: edge e+1
  const int c8 = (l & 31) * 8;    // this lane's 8-col strip

  int ea = rowptr[v],                e1a = rowptr[v + 1];
  int eb = rowptr[(NN + 1) + v],     e1b = rowptr[(NN + 1) + v + 1];
  int ec = rowptr[2 * (NN + 1) + v], e1c = rowptr[2 * (NN + 1) + v + 1];
  const int2* cea = csr_e;
  const int2* ceb = csr_e + (size_t)NE;
  const int2* cec = csr_e + (size_t)2 * NE;

  float a[NR][8];
#pragma unroll
  for (int r = 0; r < NR; ++r)
#pragma unroll
    for (int j = 0; j < 8; ++j) a[r][j] = 0.f;

  while (ea < e1a || eb < e1b || ec < e1c) {
    if (ea < e1a) {
      if (ea + half < e1a) {
        int2 p = cea[ea + half];
        float w = __int_as_float(p.y);
        ushortx8 xv = *(const ushortx8*)&x[(size_t)p.x * NF + c8];
#pragma unroll
        for (int j = 0; j < 8; ++j) a[0][j] += w * bfu2f(xv[j]);
      }
      ea += 2;
    }
    if (eb < e1b) {
      if (eb + half < e1b) {
        int2 p = ceb[eb + half];
        float w = __int_as_float(p.y);
        ushortx8 xv = *(const ushortx8*)&x[(size_t)p.x * NF + c8];
#pragma unroll
        for (int j = 0; j < 8; ++j) a[1][j] += w * bfu2f(xv[j]);
      }
      eb += 2;
    }
    if (ec < e1c) {
      if (ec + half < e1c) {
        int2 p = cec[ec + half];
        float w = __int_as_float(p.y);
        ushortx8 xv = *(const ushortx8*)&x[(size_t)p.x * NF + c8];
#pragma unroll
        for (int j = 0; j < 8; ++j) a[2][j] += w * bfu2f(xv[j]);
      }
      ec += 2;
    }
  }

#pragma unroll
  for (int r = 0; r < NR; ++r)
#pragma unroll
    for (int j = 0; j < 8; ++j) a[r][j] += __shfl_xor(a[r][j], 32);

  if (l < 32) {
#pragma unroll
    for (int r = 0; r < NR; ++r) {
      float nd = n_dst[r * NN + v];
      ushortx8 o;
#pragma unroll
      for (int j = 0; j < 8; ++j) o[j] = f2bfu(a[r][j] * nd);
      __builtin_nontemporal_store(o, (ushortx8*)&agg[(size_t)v * NK + r * NF + c8]);
    }
  }
}

// ---------------- GEMM: [M,768] @ [768,256], BN=256, double-buffered LDS ----------------
// T3-minimum 2-phase: stage tile t+1 BEFORE computing tile t; one vmcnt(0)+barrier
// per K-step (staging latency hides under MFMA).

__global__ __launch_bounds__(256, 2) void gemm_kernel(
    const unsigned short* __restrict__ A,    // [M][768] bf16
    const unsigned short* __restrict__ Bt,   // [256][768] bf16 (B^T: [col][K])
    const float* __restrict__ bias,          // [256]
    unsigned short* __restrict__ C,          // [M][256] bf16
    int M, int relu) {
  __shared__ unsigned short ldsA[2][128 * 32];   // [buf][row][32]
  __shared__ unsigned short ldsB[2][256 * 32];   // [buf][col][32]
  const int tid = threadIdx.x;
  const int l = tid & 63, wid = tid >> 6;
  const int row0 = blockIdx.x * 128;
  const int c0 = wid * 64;                    // wave's 64-col strip

  floatx4 acc[8][4];
#pragma unroll
  for (int i = 0; i < 8; ++i)
#pragma unroll
    for (int j = 0; j < 4; ++j)
#pragma unroll
      for (int q = 0; q < 4; ++q) acc[i][j][q] = 0.f;

  const int fr = l & 15, fk = (l >> 4) * 8;

  auto stage = [&](int b, int kt) {
    const int k0 = kt * 32;
    int u = wid * 64 + l;                     // A pass 0: units 0..255
    int arow = row0 + (u >> 2);
    if (arow >= M) arow = M - 1;
    gload16(A + (size_t)arow * NK + k0 + (u & 3) * 8, &ldsA[b][u * 8]);
    u += 256;                                 // A pass 1: units 256..511
    arow = row0 + (u >> 2);
    if (arow >= M) arow = M - 1;
    gload16(A + (size_t)arow * NK + k0 + (u & 3) * 8, &ldsA[b][u * 8]);
#pragma unroll
    for (int p = 0; p < 4; ++p) {             // B: 1024 units
      int uu = p * 256 + wid * 64 + l;
      gload16(Bt + (size_t)(uu >> 2) * NK + k0 + (uu & 3) * 8, &ldsB[b][uu * 8]);
    }
  };

  stage(0, 0);
  asm volatile("s_waitcnt vmcnt(0)" ::: "memory");
  __syncthreads();

  int cur = 0;
  for (int kt = 0; kt < NK / 32; ++kt) {
    if (kt + 1 < NK / 32) stage(cur ^ 1, kt + 1);

    short8 af[8], bf[4];
#pragma unroll
    for (int m = 0; m < 8; ++m)
      af[m] = *(const short8*)&ldsA[cur][(m * 16 + fr) * 32 + fk];
#pragma unroll
    for (int n = 0; n < 4; ++n)
      bf[n] = *(const short8*)&ldsB[cur][(c0 + n * 16 + fr) * 32 + fk];
#pragma unroll
    for (int m = 0; m < 8; ++m)
#pragma unroll
      for (int n = 0; n < 4; ++n)
        acc[m][n] = __builtin_amdgcn_mfma_f32_16x16x32_bf16(af[m], bf[n], acc[m][n], 0, 0, 0);

    asm volatile("s_waitcnt vmcnt(0)" ::: "memory");
    __syncthreads();
    cur ^= 1;
  }

  const int fq = l >> 4;
#pragma unroll
  for (int m = 0; m < 8; ++m) {
#pragma unroll
    for (int n = 0; n < 4; ++n) {
      int col = c0 + n * 16 + fr;
      float bv = bias[col];
#pragma unroll
      for (int q = 0; q < 4; ++q) {
        int row = row0 + m * 16 + fq * 4 + q;
        if (row < M) {
          float vv = acc[m][n][q] + bv;
          if (relu) vv = fmaxf(vv, 0.f);
          C[(size_t)row * NF + col] = f2bfu(vv);
        }
      }
    }
  }
}

// ---------------- pooling ----------------

__global__ __launch_bounds__(256) void pool_kernel(
    const unsigned short* __restrict__ h2, const int* __restrict__ gid,
    float* __restrict__ poolsum) {
  int c = threadIdx.x;                 // column 0..255
  int v0 = blockIdx.x * 256;
  int vend = min(v0 + 256, NN);
  float acc = 0.f;
  int curg = -1;
  for (int v = v0; v < vend; ++v) {
    int g = gid[v];                    // sorted -> few runs per chunk
    if (g != curg) {
      if (curg >= 0) atomicAdd(&poolsum[curg * NF + c], acc);
      curg = g; acc = 0.f;
    }
    acc += bfu2f(h2[(size_t)v * NF + c]);
  }
  if (curg >= 0) atomicAdd(&poolsum[curg * NF + c], acc);
}

__global__ __launch_bounds__(256) void final_kernel(
    const float* __restrict__ poolsum, const int* __restrict__ gcount,
    float* __restrict__ out) {
  int g = blockIdx.x, c = threadIdx.x;
  out[g * NF + c] = poolsum[g * NF + c] / fmaxf((float)gcount[g], 1.f);
}

// ---------------- launch ----------------

extern "C" void kernel_launch(void* const* d_in, const int* in_sizes, int n_in,
                              void* d_out, int out_size, void* d_ws, size_t ws_size,
                              hipStream_t stream) {
  const float* feat = (const float*)d_in[0];
  const int* src = (const int*)d_in[1];
  const int* dst = (const int*)d_in[2];
  const int* gid = (const int*)d_in[3];
  const float* W1 = (const float*)d_in[4];
  const float* b1 = (const float*)d_in[5];
  const float* W2 = (const float*)d_in[6];
  const float* b2 = (const float*)d_in[7];
  float* out = (float*)d_out;

  char* ws = (char*)d_ws;
  size_t off = 0;
  auto alloc = [&](size_t bytes) -> void* {
    void* p = ws + off;
    off = (off + bytes + 255) & ~(size_t)255;
    return p;
  };

  // zero-initialized block (single memset)
  int* deg_out = (int*)alloc((size_t)NR * NN * 4);
  int* deg_in  = (int*)alloc((size_t)NR * NN * 4);
  float* poolsum = (float*)alloc((size_t)NG * NF * 4);
  size_t zero_bytes = off;

  int* cursor  = (int*)alloc((size_t)NR * (NN + 1) * 4);
  int* gcount  = (int*)alloc((size_t)NG * 4);
  int* blocksum = (int*)alloc((size_t)NR * SCAN_NB * 4);
  float* n_src = (float*)alloc((size_t)NR * NN * 4);
  float* n_dst = (float*)alloc((size_t)NR * NN * 4);
  int* rowptr  = (int*)alloc((size_t)NR * (NN + 1) * 4);
  int2* csr_e  = (int2*)alloc((size_t)NR * NE * 8);
  unsigned short* wt1 = (unsigned short*)alloc((size_t)NF * NK * 2);
  unsigned short* wt2 = (unsigned short*)alloc((size_t)NF * NK * 2);
  float* bs1 = (float*)alloc(NF * 4);
  float* bs2 = (float*)alloc(NF * 4);
  unsigned short* featbf = (unsigned short*)alloc((size_t)NN * NF * 2);
  unsigned short* h1 = (unsigned short*)alloc((size_t)NN * NF * 2);
  unsigned short* h2 = (unsigned short*)alloc((size_t)NN * NF * 2);
  unsigned short* agg = (unsigned short*)alloc((size_t)NN * NK * 2);
  (void)ws_size; (void)in_sizes; (void)n_in; (void)out_size;

  hipMemsetAsync(d_ws, 0, zero_bytes, stream);

  dim3 eg((NE + 255) / 256, NR);
  degree_kernel<<<eg, 256, 0, stream>>>(src, dst, deg_out, deg_in);
  gcount_kernel<<<1, 128, 0, stream>>>(gid, gcount);
  norm_kernel<<<(NR * NN + 255) / 256, 256, 0, stream>>>(deg_out, deg_in, n_src, n_dst);
  scan_phaseA<<<dim3(SCAN_NB, NR), 256, 0, stream>>>(deg_in, blocksum);
  scan_phaseB<<<NR, 128, 0, stream>>>(blocksum, rowptr);
  scan_phaseC<<<dim3(SCAN_NB, NR), 256, 0, stream>>>(deg_in, blocksum, rowptr);
  hipMemcpyAsync(cursor, rowptr, (size_t)NR * (NN + 1) * 4,
                 hipMemcpyDeviceToDevice, stream);
  scatter_kernel<<<eg, 256, 0, stream>>>(src, dst, cursor, n_src, csr_e);

  prep_w_kernel<<<(2 * NR * NF * NF) / 256, 256, 0, stream>>>(W1, W2, wt1, wt2);
  prep_bias_kernel<<<2, 256, 0, stream>>>(b1, b2, bs1, bs2);
  cast_kernel<<<(NN * NF / 4 + 255) / 256, 256, 0, stream>>>(feat, featbf, NN * NF / 4);

  // layer 1
  spmm_kernel<<<(NN + 3) / 4, 256, 0, stream>>>(featbf, rowptr, csr_e, n_dst, agg);
  gemm_kernel<<<(NN + 127) / 128, 256, 0, stream>>>(agg, wt1, bs1, h1, NN, 1);
  // layer 2
  spmm_kernel<<<(NN + 3) / 4, 256, 0, stream>>>(h1, rowptr, csr_e, n_dst, agg);
  gemm_kernel<<<(NN + 127) / 128, 256, 0, stream>>>(agg, wt2, bs2, h2, NN, 0);
  // pooling
  pool_kernel<<<(NN + 255) / 256, 256, 0, stream>>>(h2, gid, poolsum);
  final_kernel<<<NG, 256, 0, stream>>>(poolsum, gcount, out);
}